// Round 5
// baseline (17683.710 us; speedup 1.0000x reference)
//
#include <hip/hip_runtime.h>
#include <math.h>

#define B_  64
#define T_  512
#define D0_ 128
#define H_  512
#define G3_ 1536
#define HSTR 512
#define BKg 32
#define SENT 0x7FC00000u   // NaN sentinel; |h|<1 strictly so real h never matches

typedef short short8 __attribute__((ext_vector_type(8)));
typedef float f32x4 __attribute__((ext_vector_type(4)));

__device__ __forceinline__ float fast_sig(float x) {
  return __builtin_amdgcn_rcpf(1.f + __expf(-x));
}
__device__ __forceinline__ float fast_tanh(float x) {
  // 1 - 2/(1+e^{2x}); saturates correctly at +/-inf
  return 1.f - 2.f * __builtin_amdgcn_rcpf(1.f + __expf(2.f * x));
}

// ---------------- scan kernel (R1 structure + R15 chunk-gated exchange) ---
// 256 blocks = 16 groups x 16 blocks; data-as-flag exchange (hist pre-filled
// with SENT; consumers poll h words; producer b32 stores are the signal).
// R11: 768 threads (12 waves), 1 row x 64 k per thread; 3 waves/SIMD.
// R12 post-mortem: XCD-colocation: FETCH -57% but dur +4.5% -> latency-bound
// through coherence point; g=blk>>4 mapping kept.
// R13 post-mortem: 512-block dual-set pipelining: poll spin is an adversarial
// co-tenant (per-step latency 2x). 256 blocks only.
// R14 post-mortem: s_sleep(4) + b64 pair store + setprio bundle = +3% dur.
// All three reverted (sleep quantizes detection; pair store appeared in both
// regressing rounds).
// R15: chunk-gated staging + incremental dot. h_prev = 16 chunks of 32 cols
// (one per producer). LDS counter per chunk (release inc / acquire spin);
// each thread's k-window is CONTIGUOUS 64 k = chunks {2s, 2s+1}, FMA'd in
// fixed order as flags land. Removes the stage->dot barrier so early-chunk
// FMA overlaps late-chunk arrival (last chunk gates ~32k FMA, not 1536 cy).
// Own-block cols are staged by its own gates (skip 64/1024 polls after the
// first step of each dispatch).
// LESSON (R10): poll traffic not increased; trailing sync kept.
__global__ __launch_bounds__(768, 3) void scan_kernel(
    const float* __restrict__ Whh, const float* __restrict__ bhh,
    const float* __restrict__ gx, float* __restrict__ hist,
    int t0, int tc, int gxt0, int gxT)
{
  __shared__ float hsh[4 * HSTR];
  __shared__ float ghsh[96 * 5];
  __shared__ float bsh[96];
  __shared__ int   cnt[16];

  const int tid = threadIdx.x;
  const int blk = blockIdx.x;
  const int g = blk >> 4, c = blk & 15;   // R11 mapping (measured best)
  const int j0 = c << 5;
  const int bbase = g << 2;

  const int r0 = tid >> 3, s = tid & 7;   // 96 rows x 8 k-slices
  const int grow0 = (r0 >> 5) * H_ + j0 + (r0 & 31);

  // contiguous k-window [s*64, s*64+64) = chunks 2s, 2s+1
  float w[64];
  {
    const float* R0 = Whh + (size_t)grow0 * H_ + (s << 6);
    #pragma unroll
    for (int kk = 0; kk < 16; ++kk)
      *(float4*)&w[kk * 4] = *(const float4*)(R0 + (kk << 2));
  }
  if (tid < 96)
    bsh[tid] = bhh[(tid >> 5) * H_ + j0 + (tid & 31)];

  size_t go0 = 0;
  if (tid < 128) {
    int bb = tid >> 5, j = tid & 31;
    go0 = ((size_t)(bbase + bb) * gxT) * (size_t)G3_ + j0 + j;
  }

  // poll duty: round-0 pair (all 768): bb0 = tid>>8 (0..2), e0, kc0.
  // round-1 pair (tid<256): bb=3, e1 = tid>>4, kc1.
  const int kc0 = tid & 15, e0 = (tid >> 4) & 15, bb0 = tid >> 8;
  const int kc1 = tid & 15, e1 = tid >> 4;     // valid when tid < 256
  const int k0c = s << 1, k1c = (s << 1) + 1;  // chunks this thread consumes

  // entry init: mid-sequence dispatch (t0>0) must poll ALL chunks (incl. own:
  // hsh/LDS is fresh, own cols only exist in global hist).
  if (tid < 16) cnt[tid] = 0;
  __syncthreads();

  for (int t = t0; t < t0 + tc; ++t) {
    // ---- gx prefetch (independent of exchange) ----
    float gxr = 0.f, gxz = 0.f, gxn = 0.f;
    if (tid < 128) {
      size_t go = go0 + (size_t)(t - gxt0) * (size_t)G3_;
      gxr = gx[go]; gxz = gx[go + 512]; gxn = gx[go + 1024];
    }

    if (t == 0) {
      for (int idx = tid; idx < 2048; idx += 768)
        hsh[(idx >> 9) * HSTR + (idx & 511)] = 0.f;
      if (tid < 16) cnt[tid] = 64;
      __syncthreads();
    } else {
      // first iteration of a dispatch polls own chunk too (LDS is fresh)
      const bool pollOwn = (t == t0);
      bool need0 = pollOwn || (kc0 != c);
      bool need1 = (tid < 256) && (pollOwn || (kc1 != c));
      const unsigned long long* p0 = (const unsigned long long*)
          (hist + ((size_t)(bbase + bb0) * T_ + (t - 1)) * H_) +
          ((kc0 << 4) + e0);
      const unsigned long long* p1 = (const unsigned long long*)
          (hist + ((size_t)(bbase + 3) * T_ + (t - 1)) * H_) +
          ((kc1 << 4) + e1);
      while (need0 || need1) {
        unsigned long long v0 = 0, v1 = 0;
        if (need0)
          v0 = __hip_atomic_load(p0, __ATOMIC_RELAXED,
                                 __HIP_MEMORY_SCOPE_AGENT);
        if (need1)
          v1 = __hip_atomic_load(p1, __ATOMIC_RELAXED,
                                 __HIP_MEMORY_SCOPE_AGENT);
        if (need0) {
          unsigned lo = (unsigned)v0, hi = (unsigned)(v0 >> 32);
          if (lo != SENT && hi != SENT) {
            *(float2*)&hsh[bb0 * HSTR + (((kc0 << 4) + e0) << 1)] =
                make_float2(__uint_as_float(lo), __uint_as_float(hi));
            __hip_atomic_fetch_add(&cnt[kc0], 1, __ATOMIC_RELEASE,
                                   __HIP_MEMORY_SCOPE_WORKGROUP);
            need0 = false;
          }
        }
        if (need1) {
          unsigned lo = (unsigned)v1, hi = (unsigned)(v1 >> 32);
          if (lo != SENT && hi != SENT) {
            *(float2*)&hsh[3 * HSTR + (((kc1 << 4) + e1) << 1)] =
                make_float2(__uint_as_float(lo), __uint_as_float(hi));
            __hip_atomic_fetch_add(&cnt[kc1], 1, __ATOMIC_RELEASE,
                                   __HIP_MEMORY_SCOPE_WORKGROUP);
            need1 = false;
          }
        }
      }
    }

    // ---- chunk-gated dots: no barrier; FMA each chunk as its flag lands ----
    float acc[4];
    // chunk k0c (k = k0c*32 .. +32), w[0..32)
    while (__hip_atomic_load(&cnt[k0c], __ATOMIC_ACQUIRE,
                             __HIP_MEMORY_SCOPE_WORKGROUP) < 64) {}
    #pragma unroll
    for (int b = 0; b < 4; ++b) {
      const float* hb = hsh + b * HSTR + (k0c << 5);
      float a0 = 0.f, a1 = 0.f;
      #pragma unroll
      for (int kk = 0; kk < 8; kk += 2) {
        float4 h0 = *(const float4*)(hb + kk * 4);
        float4 h1 = *(const float4*)(hb + kk * 4 + 4);
        a0 += w[kk*4+0]*h0.x; a0 += w[kk*4+1]*h0.y;
        a0 += w[kk*4+2]*h0.z; a0 += w[kk*4+3]*h0.w;
        a1 += w[kk*4+4]*h1.x; a1 += w[kk*4+5]*h1.y;
        a1 += w[kk*4+6]*h1.z; a1 += w[kk*4+7]*h1.w;
      }
      acc[b] = a0 + a1;
    }
    // chunk k1c (k = k1c*32 .. +32), w[32..64)
    while (__hip_atomic_load(&cnt[k1c], __ATOMIC_ACQUIRE,
                             __HIP_MEMORY_SCOPE_WORKGROUP) < 64) {}
    #pragma unroll
    for (int b = 0; b < 4; ++b) {
      const float* hb = hsh + b * HSTR + (k1c << 5);
      float a0 = 0.f, a1 = 0.f;
      #pragma unroll
      for (int kk = 0; kk < 8; kk += 2) {
        float4 h0 = *(const float4*)(hb + kk * 4);
        float4 h1 = *(const float4*)(hb + kk * 4 + 4);
        a0 += w[32+kk*4+0]*h0.x; a0 += w[32+kk*4+1]*h0.y;
        a0 += w[32+kk*4+2]*h0.z; a0 += w[32+kk*4+3]*h0.w;
        a1 += w[32+kk*4+4]*h1.x; a1 += w[32+kk*4+5]*h1.y;
        a1 += w[32+kk*4+6]*h1.z; a1 += w[32+kk*4+7]*h1.w;
      }
      acc[b] += a0 + a1;
    }

    #pragma unroll
    for (int m = 1; m < 8; m <<= 1) {
      #pragma unroll
      for (int b = 0; b < 4; ++b)
        acc[b] += __shfl_xor(acc[b], m, 64);
    }
    if (s < 4) {
      float v = (s & 2) ? ((s & 1) ? acc[3] : acc[2])
                        : ((s & 1) ? acc[1] : acc[0]);
      ghsh[r0 * 5 + s] = v;
    }
    __syncthreads();   // all FMA/spins done; ghsh ready; cnt dead

    // ---- gates + h_new; also stage own cols + reset chunk counters ----
    if (tid < 16) cnt[tid] = (tid == c) ? 64 : 0;   // for step t+1
    if (tid < 128) {
      int bb = tid >> 5, j = tid & 31;
      float ghr = ghsh[ j       * 5 + bb] + bsh[j];
      float ghz = ghsh[(32 + j) * 5 + bb] + bsh[32 + j];
      float ghn = ghsh[(64 + j) * 5 + bb] + bsh[64 + j];
      float rg = fast_sig(gxr + ghr);
      float zg = fast_sig(gxz + ghz);
      float ng = fast_tanh(gxn + rg * ghn);
      float hp = hsh[bb * HSTR + j0 + j];
      float hnew = (1.f - zg) * ng + zg * hp;
      __hip_atomic_store(
          (unsigned*)(hist + ((size_t)(bbase + bb) * T_ + t) * H_) + j0 + j,
          __float_as_uint(hnew), __ATOMIC_RELAXED, __HIP_MEMORY_SCOPE_AGENT);
      hsh[bb * HSTR + j0 + j] = hnew;   // own chunk staged locally
    }
    __syncthreads();   // protect hsh/ghsh/cnt reuse next step (R10)
  }
}

// ---------------- sentinel fill: hist rows [t0, t0+tc) for all batches ----
__global__ __launch_bounds__(256) void sent_fill(float* hist, int t0, int tc) {
  int i = blockIdx.x * 256 + threadIdx.x;          // uint4 index
  int per = tc * (H_ >> 2);                        // uint4 per batch
  if (i < B_ * per) {
    int b = i / per, r = i % per;
    uint4* p = (uint4*)(hist + ((size_t)b * T_ + t0) * H_) + r;
    *p = make_uint4(SENT, SENT, SENT, SENT);
  }
}

// ---------------- fp32 -> bf16 hi/lo split ----------------
__device__ __forceinline__ unsigned short f2bf_rne(float f) {
  unsigned u = __float_as_uint(f);
  unsigned r = (u + 0x7fffu + ((u >> 16) & 1u)) >> 16;
  return (unsigned short)r;
}
__device__ __forceinline__ float bf2f(unsigned short h) {
  return __uint_as_float(((unsigned)h) << 16);
}

__global__ __launch_bounds__(256) void conv_split(
    const float* __restrict__ A, int lda, int t0, int tc, int ltc,
    unsigned short* __restrict__ Ah, unsigned short* __restrict__ Al)
{
  int idx = blockIdx.x * 256 + threadIdx.x;
  int m = idx / (lda >> 2), kq = idx % (lda >> 2);
  const float4 v = *(const float4*)
      (A + ((size_t)(m >> ltc) * T_ + t0 + (m & (tc - 1))) * lda + (kq << 2));
  unsigned short h0 = f2bf_rne(v.x), h1 = f2bf_rne(v.y),
                 h2 = f2bf_rne(v.z), h3 = f2bf_rne(v.w);
  unsigned short l0 = f2bf_rne(v.x - bf2f(h0)), l1 = f2bf_rne(v.y - bf2f(h1)),
                 l2 = f2bf_rne(v.z - bf2f(h2)), l3 = f2bf_rne(v.w - bf2f(h3));
  size_t o = (size_t)m * lda + (kq << 2);
  *(ushort4*)(Ah + o) = make_ushort4(h0, h1, h2, h3);
  *(ushort4*)(Al + o) = make_ushort4(l0, l1, l2, l3);
}

// ---------------- split-bf16 MFMA GEMM (double-buffered, pipelined) -------
__global__ __launch_bounds__(256, 2) void gemm_mfma(
    const unsigned short* __restrict__ Ah, const unsigned short* __restrict__ Al,
    const unsigned short* __restrict__ Bh, const unsigned short* __restrict__ Bl,
    const float* __restrict__ bias, float* __restrict__ gxout, int K)
{
  __shared__ unsigned short sAh[2][128 * BKg], sAl[2][128 * BKg];
  __shared__ unsigned short sBh[2][128 * BKg], sBl[2][128 * BKg];

  const int tid = threadIdx.x;
  const int m0 = blockIdx.x << 7, n0 = blockIdx.y << 7;
  const int wave = tid >> 6, lane = tid & 63;
  const int wr = (wave & 1) << 6, wc = (wave >> 1) << 6;
  const int fm = lane & 15, kh = lane >> 4;

  const int srow = tid >> 2, sq = tid & 3;
  const int lofs0 = srow * BKg + (sq << 3);
  const int lofs1 = (64 + srow) * BKg + (sq << 3);

  f32x4 acc[4][4];
  #pragma unroll
  for (int i = 0; i < 4; ++i)
    #pragma unroll
    for (int j = 0; j < 4; ++j)
      acc[i][j] = (f32x4){0.f, 0.f, 0.f, 0.f};

  float4 pAh[2], pAl[2], pBh[2], pBl[2];
  #define PREFETCH(k0)                                                        \
    {                                                                         \
      size_t a0 = (size_t)(m0 + srow) * K + (k0) + (sq << 3);                 \
      size_t a1 = (size_t)(m0 + 64 + srow) * K + (k0) + (sq << 3);            \
      size_t b0 = (size_t)(n0 + srow) * K + (k0) + (sq << 3);                 \
      size_t b1 = (size_t)(n0 + 64 + srow) * K + (k0) + (sq << 3);            \
      pAh[0] = *(const float4*)&Ah[a0]; pAh[1] = *(const float4*)&Ah[a1];     \
      pAl[0] = *(const float4*)&Al[a0]; pAl[1] = *(const float4*)&Al[a1];     \
      pBh[0] = *(const float4*)&Bh[b0]; pBh[1] = *(const float4*)&Bh[b1];     \
      pBl[0] = *(const float4*)&Bl[b0]; pBl[1] = *(const float4*)&Bl[b1];     \
    }
  #define STORE_LDS(buf)                                                      \
    {                                                                         \
      *(float4*)&sAh[buf][lofs0] = pAh[0]; *(float4*)&sAh[buf][lofs1] = pAh[1];\
      *(float4*)&sAl[buf][lofs0] = pAl[0]; *(float4*)&sAl[buf][lofs1] = pAl[1];\
      *(float4*)&sBh[buf][lofs0] = pBh[0]; *(float4*)&sBh[buf][lofs1] = pBh[1];\
      *(float4*)&sBl[buf][lofs0] = pBl[0]; *(float4*)&sBl[buf][lofs1] = pBl[1];\
    }

  PREFETCH(0);
  STORE_LDS(0);
  int buf = 0;

  for (int k0 = 0; k0 < K; k0 += BKg) {
    __syncthreads();
    const bool more = (k0 + BKg) < K;
    if (more) PREFETCH(k0 + BKg);

    short8 fAh[4], fAl[4], fBh[4], fBl[4];
    #pragma unroll
    for (int i = 0; i < 4; ++i) {
      int ao = (wr + i * 16 + fm) * BKg + (kh << 3);
      int bo = (wc + i * 16 + fm) * BKg + (kh << 3);
      fAh[i] = *(const short8*)&sAh[buf][ao];
      fAl[i] = *(const short8*)&sAl[buf][ao];
      fBh[i] = *(const short8*)&sBh[buf][bo];
      fBl[i] = *(const short8*)&sBl[buf][bo];
    }
    #pragma unroll
    for (int i = 0; i < 4; ++i)
      #pragma unroll
      for (int j = 0; j < 4; ++j) {
        acc[i][j] = __builtin_amdgcn_mfma_f32_16x16x32_bf16(
            fAh[i], fBh[j], acc[i][j], 0, 0, 0);
        acc[i][j] = __builtin_amdgcn_mfma_f32_16x16x32_bf16(
            fAh[i], fBl[j], acc[i][j], 0, 0, 0);
        acc[i][j] = __builtin_amdgcn_mfma_f32_16x16x32_bf16(
            fAl[i], fBh[j], acc[i][j], 0, 0, 0);
      }
    if (more) {
      STORE_LDS(buf ^ 1);
      buf ^= 1;
    }
  }

  #pragma unroll
  for (int j = 0; j < 4; ++j) {
    int col = n0 + wc + j * 16 + fm;
    float bv = bias[col];
    #pragma unroll
    for (int i = 0; i < 4; ++i) {
      int rowb = m0 + wr + i * 16 + (kh << 2);
      #pragma unroll
      for (int r = 0; r < 4; ++r)
        gxout[(size_t)(rowb + r) * G3_ + col] = acc[i][j][r] + bv;
    }
  }
}

// ---------------- final FC ----------------
__global__ void fc_kernel(const float* __restrict__ hist, const float* __restrict__ Wfc,
                          const float* __restrict__ bfc, float* __restrict__ out)
{
  int b = blockIdx.x, lane = threadIdx.x;
  const float* h = hist + ((size_t)b*T_ + (T_-1))*H_;
  float acc = 0.f;
  for (int j = lane; j < H_; j += 64) acc += h[j]*Wfc[j];
  #pragma unroll
  for (int off = 32; off; off >>= 1) acc += __shfl_down(acc, off, 64);
  if (lane == 0) out[b] = acc + bfc[0];
}

extern "C" void kernel_launch(void* const* d_in, const int* in_sizes, int n_in,
                              void* d_out, int out_size, void* d_ws, size_t ws_size,
                              hipStream_t stream)
{
  const float* X    = (const float*)d_in[0];
  const float* Wih0 = (const float*)d_in[1];
  const float* Whh0 = (const float*)d_in[2];
  const float* bih0 = (const float*)d_in[3];
  const float* bhh0 = (const float*)d_in[4];
  const float* Wih1 = (const float*)d_in[5];
  const float* Whh1 = (const float*)d_in[6];
  const float* bih1 = (const float*)d_in[7];
  const float* bhh1 = (const float*)d_in[8];
  const float* Wfc  = (const float*)d_in[9];
  const float* bfc  = (const float*)d_in[10];

  float* hist = (float*)((char*)d_ws + 4096);
  const size_t histB = (size_t)B_*T_*H_*4;

  const size_t bB = (size_t)G3_ * 512 * 2;
  int tcg = 128;
  {
    size_t fixed = 4096 + histB + 2 * bB;
    if      (ws_size >= fixed + (size_t)B_*512*((size_t)G3_*4 + 512*4)) tcg = 512;
    else if (ws_size >= fixed + (size_t)B_*256*((size_t)G3_*4 + 512*4)) tcg = 256;
  }
  int ltc = 31 - __builtin_clz((unsigned)tcg);

  float* gxbuf = (float*)((char*)d_ws + 4096 + histB);
  const size_t gxB = (size_t)B_*tcg*G3_*4;
  unsigned short* Ahb = (unsigned short*)((char*)gxbuf + gxB);
  const size_t aB = (size_t)B_*tcg*512*2;
  unsigned short* Alb = (unsigned short*)((char*)Ahb + aB);
  unsigned short* Bhb = (unsigned short*)((char*)Alb + aB);
  unsigned short* Blb = (unsigned short*)((char*)Bhb + bB);

  const int sentGridFull = (B_ * T_ * (H_ >> 2) + 255) / 256;
  const int sentGridChunk = (B_ * tcg * (H_ >> 2) + 255) / 256;

  // layer 0: whole hist -> sentinel before its first scan (conv/gemm read X)
  hipLaunchKernelGGL(sent_fill, dim3(sentGridFull), dim3(256), 0, stream,
                     hist, 0, T_);

  for (int lay = 0; lay < 2; ++lay) {
    const float* A   = lay ? (const float*)hist : X;
    int lda          = lay ? H_ : D0_;
    const float* Wih = lay ? Wih1 : Wih0;
    const float* bih = lay ? bih1 : bih0;
    const float* Whh = lay ? Whh1 : Whh0;
    const float* bhh = lay ? bhh1 : bhh0;

    hipLaunchKernelGGL(conv_split, dim3((G3_*lda/4)/256), dim3(256), 0, stream,
                       Wih, lda, 0, 1 << 30, 30, Bhb, Blb);

    for (int t0g = 0; t0g < T_; t0g += tcg) {
      int M = B_ * tcg;
      // conv reads this chunk's hist rows (layer 1) BEFORE they're sentineled
      hipLaunchKernelGGL(conv_split, dim3((M*lda/4)/256), dim3(256), 0, stream,
                         A, lda, t0g, tcg, ltc, Ahb, Alb);
      if (lay == 1)   // re-sentinel the rows this chunk's scan will write
        hipLaunchKernelGGL(sent_fill, dim3(sentGridChunk), dim3(256), 0, stream,
                           hist, t0g, tcg);
      dim3 ggrid(M >> 7, G3_ >> 7);
      hipLaunchKernelGGL(gemm_mfma, ggrid, dim3(256), 0, stream,
                         Ahb, Alb, Bhb, Blb, bih, gxbuf, lda);
      hipLaunchKernelGGL(scan_kernel, dim3(256), dim3(768), 0, stream,
                         Whh, bhh, (const float*)gxbuf, hist, t0g, tcg, t0g, tcg);
    }
  }

  hipLaunchKernelGGL(fc_kernel, dim3(64), dim3(64), 0, stream,
                     (const float*)hist, Wfc, bfc, (float*)d_out);
}

// Round 6
// 4892.840 us; speedup vs baseline: 3.6142x; 3.6142x over previous
//
#include <hip/hip_runtime.h>
#include <math.h>

#define B_  64
#define T_  512
#define D0_ 128
#define H_  512
#define G3_ 1536
#define HSTR 512
#define BKg 32
#define SENT 0x7FC00000u   // NaN sentinel; |h|<1 strictly so real h never matches

typedef short short8 __attribute__((ext_vector_type(8)));
typedef float f32x4 __attribute__((ext_vector_type(4)));

__device__ __forceinline__ float fast_sig(float x) {
  return __builtin_amdgcn_rcpf(1.f + __expf(-x));
}
__device__ __forceinline__ float fast_tanh(float x) {
  // 1 - 2/(1+e^{2x}); saturates correctly at +/-inf
  return 1.f - 2.f * __builtin_amdgcn_rcpf(1.f + __expf(2.f * x));
}

// ---------------- fused dual-layer scan (R16) -----------------------------
// 256 blocks = 16 groups x 16 col-chunks; each block runs layer-0 chunk s
// AND layer-1 chunk s-1 in ONE instruction stream (R13's extra-block overlap
// failed on CU co-scheduling; same-block fusion avoids it; block count and
// poll protocol per layer identical to the proven R1).
// 512 threads, __launch_bounds__(512,2): 2 waves/SIMD -> ~256 reg/thread
// budget; dual W = 192 f32/thread + temps fits (the R4/R9 spill wall was the
// 3-waves/SIMD 170 cap).
// 3 slots/thread: q = tid + 512*i over [0,1536) = 2 layers x 96 rows x 8
// k-slices. R1's strided-k layout + 8-lane shfl reduce kept EXACTLY ->
// numerics identical to passing R1.
// R15 post-mortem: NO LDS-counter gating (1.47e9 bank conflicts). Barriers
// and data-as-flag polls exactly as R1. LESSON R10: trailing sync kept.
__global__ __launch_bounds__(512, 2) void scan_fused(
    const float* __restrict__ Whh0, const float* __restrict__ bhh0,
    const float* __restrict__ gxA,  float* __restrict__ histA, int t0A, int tcA,
    const float* __restrict__ Whh1, const float* __restrict__ bhh1,
    const float* __restrict__ gxB,  float* __restrict__ histB, int t0B, int tcB)
{
  __shared__ float hsh[2][4][HSTR];
  __shared__ float ghsh[2][96 * 5];
  __shared__ float bsh[2][96];

  const int tid = threadIdx.x;
  const int blk = blockIdx.x;
  const int g = blk >> 4, c = blk & 15;   // R11 mapping (measured best)
  const int j0 = c << 5;
  const int bbase = g << 2;
  const int s = tid & 7;

  // slot rows: slot0 lay0 rr0=tid>>3 (0..63); slot1: tid<256 -> lay0
  // rr=64+(tid>>3) else lay1 rr=(tid-256)>>3; slot2 lay1 rr2=(tid+256)>>3.
  const int rr0 = tid >> 3;
  const bool s1L0 = (tid < 256);
  const int rr1 = s1L0 ? (64 + (tid >> 3)) : ((tid - 256) >> 3);
  const int rr2 = (tid + 256) >> 3;

  float w0[64], w1[64], w2[64];
  {
    const float* R = Whh0 + (size_t)((rr0 >> 5) * H_ + j0 + (rr0 & 31)) * H_ + (s << 2);
    #pragma unroll
    for (int kk = 0; kk < 16; ++kk)
      *(float4*)&w0[kk * 4] = *(const float4*)(R + kk * 32);
  }
  {
    const float* Wb = s1L0 ? Whh0 : Whh1;
    const float* R = Wb + (size_t)((rr1 >> 5) * H_ + j0 + (rr1 & 31)) * H_ + (s << 2);
    #pragma unroll
    for (int kk = 0; kk < 16; ++kk)
      *(float4*)&w1[kk * 4] = *(const float4*)(R + kk * 32);
  }
  {
    const float* R = Whh1 + (size_t)((rr2 >> 5) * H_ + j0 + (rr2 & 31)) * H_ + (s << 2);
    #pragma unroll
    for (int kk = 0; kk < 16; ++kk)
      *(float4*)&w2[kk * 4] = *(const float4*)(R + kk * 32);
  }

  if (tid < 96) bsh[0][tid] = bhh0[(tid >> 5) * H_ + j0 + (tid & 31)];
  else if (tid >= 256 && tid < 352) {
    int u = tid - 256;
    bsh[1][u] = bhh1[(u >> 5) * H_ + j0 + (u & 31)];
  }

  // gate-thread gx bases: tid<128 -> layer0, tid in [128,256) -> layer1
  size_t go0 = 0;
  if (tid < 128) {
    int bb = tid >> 5, j = tid & 31;
    go0 = ((size_t)(bbase + bb) * tcA) * (size_t)G3_ + j0 + j;
  } else if (tid < 256) {
    int u = tid - 128, bb = u >> 5, j = u & 31;
    go0 = ((size_t)(bbase + bb) * tcB) * (size_t)G3_ + j0 + j;
  }

  const float* hbase0 = &hsh[0][0][0];
  const float* hbase1s = s1L0 ? &hsh[0][0][0] : &hsh[1][0][0];
  const float* hbase2 = &hsh[1][0][0];
  float* ghs1 = s1L0 ? &ghsh[0][0] : &ghsh[1][0];

  const int tcm = tcA > tcB ? tcA : tcB;
  __syncthreads();

  for (int st = 0; st < tcm; ++st) {
    const bool actA = st < tcA, actB = st < tcB;
    const int tA = t0A + st, tB = t0B + st;

    // ---- gx prefetch (independent of exchange) ----
    float gxr = 0.f, gxz = 0.f, gxn = 0.f;
    if (tid < 128) {
      if (actA) {
        size_t go = go0 + (size_t)st * (size_t)G3_;
        gxr = gxA[go]; gxz = gxA[go + 512]; gxn = gxA[go + 1024];
      }
    } else if (tid < 256) {
      if (actB) {
        size_t go = go0 + (size_t)st * (size_t)G3_;
        gxr = gxB[go]; gxz = gxB[go + 512]; gxn = gxB[go + 1024];
      }
    }

    // ---- stage h_prev per layer: R1 data-as-flag poll (4 pair-slots) ----
    if (actA && tA == 0)
      for (int idx = tid; idx < 2048; idx += 512)
        hsh[0][idx >> 9][idx & 511] = 0.f;
    if (actB && tB == 0)
      for (int idx = tid; idx < 2048; idx += 512)
        hsh[1][idx >> 9][idx & 511] = 0.f;
    {
      unsigned rem = 0;
      if (actA && tA > 0) rem |= 3u;
      if (actB && tB > 0) rem |= 12u;
      if (rem) {
        int bbv[4], e2v[4];
        #pragma unroll
        for (int p = 0; p < 4; ++p) {
          int pidx = (p & 1) ? tid + 512 : tid;
          bbv[p] = pidx >> 8; e2v[p] = pidx & 255;
        }
        const unsigned long long* pp[4];
        pp[0] = (const unsigned long long*)(histA +
                ((size_t)(bbase + bbv[0]) * T_ + (tA - 1)) * H_) + e2v[0];
        pp[1] = (const unsigned long long*)(histA +
                ((size_t)(bbase + bbv[1]) * T_ + (tA - 1)) * H_) + e2v[1];
        pp[2] = (const unsigned long long*)(histB +
                ((size_t)(bbase + bbv[2]) * T_ + (tB - 1)) * H_) + e2v[2];
        pp[3] = (const unsigned long long*)(histB +
                ((size_t)(bbase + bbv[3]) * T_ + (tB - 1)) * H_) + e2v[3];
        while (rem) {
          unsigned long long v[4];
          #pragma unroll
          for (int p = 0; p < 4; ++p)
            if (rem & (1u << p))
              v[p] = __hip_atomic_load(pp[p], __ATOMIC_RELAXED,
                                       __HIP_MEMORY_SCOPE_AGENT);
          #pragma unroll
          for (int p = 0; p < 4; ++p)
            if (rem & (1u << p)) {
              unsigned lo = (unsigned)v[p], hi = (unsigned)(v[p] >> 32);
              if (lo != SENT && hi != SENT) {
                int L = p >> 1;
                *(float2*)&hsh[L][bbv[p]][e2v[p] << 1] =
                    make_float2(__uint_as_float(lo), __uint_as_float(hi));
                rem &= ~(1u << p);
              }
            }
        }
      }
    }
    __syncthreads();

    // ---- dots: 3 slots x 4 batches, R1 inner loop verbatim ----
    float a0[4], a1[4], a2[4];
    #pragma unroll
    for (int b = 0; b < 4; ++b) {
      const float* hb = hbase0 + b * HSTR + (s << 2);
      float x0 = 0.f, x1 = 0.f;
      #pragma unroll
      for (int kk = 0; kk < 16; kk += 2) {
        float4 h0 = *(const float4*)(hb + kk * 32);
        float4 h1 = *(const float4*)(hb + kk * 32 + 32);
        x0 += w0[kk*4+0]*h0.x; x0 += w0[kk*4+1]*h0.y;
        x0 += w0[kk*4+2]*h0.z; x0 += w0[kk*4+3]*h0.w;
        x1 += w0[kk*4+4]*h1.x; x1 += w0[kk*4+5]*h1.y;
        x1 += w0[kk*4+6]*h1.z; x1 += w0[kk*4+7]*h1.w;
      }
      a0[b] = x0 + x1;
    }
    #pragma unroll
    for (int b = 0; b < 4; ++b) {
      const float* hb = hbase1s + b * HSTR + (s << 2);
      float x0 = 0.f, x1 = 0.f;
      #pragma unroll
      for (int kk = 0; kk < 16; kk += 2) {
        float4 h0 = *(const float4*)(hb + kk * 32);
        float4 h1 = *(const float4*)(hb + kk * 32 + 32);
        x0 += w1[kk*4+0]*h0.x; x0 += w1[kk*4+1]*h0.y;
        x0 += w1[kk*4+2]*h0.z; x0 += w1[kk*4+3]*h0.w;
        x1 += w1[kk*4+4]*h1.x; x1 += w1[kk*4+5]*h1.y;
        x1 += w1[kk*4+6]*h1.z; x1 += w1[kk*4+7]*h1.w;
      }
      a1[b] = x0 + x1;
    }
    #pragma unroll
    for (int b = 0; b < 4; ++b) {
      const float* hb = hbase2 + b * HSTR + (s << 2);
      float x0 = 0.f, x1 = 0.f;
      #pragma unroll
      for (int kk = 0; kk < 16; kk += 2) {
        float4 h0 = *(const float4*)(hb + kk * 32);
        float4 h1 = *(const float4*)(hb + kk * 32 + 32);
        x0 += w2[kk*4+0]*h0.x; x0 += w2[kk*4+1]*h0.y;
        x0 += w2[kk*4+2]*h0.z; x0 += w2[kk*4+3]*h0.w;
        x1 += w2[kk*4+4]*h1.x; x1 += w2[kk*4+5]*h1.y;
        x1 += w2[kk*4+6]*h1.z; x1 += w2[kk*4+7]*h1.w;
      }
      a2[b] = x0 + x1;
    }

    #pragma unroll
    for (int m = 1; m < 8; m <<= 1)
      #pragma unroll
      for (int b = 0; b < 4; ++b) {
        a0[b] += __shfl_xor(a0[b], m, 64);
        a1[b] += __shfl_xor(a1[b], m, 64);
        a2[b] += __shfl_xor(a2[b], m, 64);
      }
    if (s < 4) {
      float v0 = (s & 2) ? ((s & 1) ? a0[3] : a0[2]) : ((s & 1) ? a0[1] : a0[0]);
      float v1 = (s & 2) ? ((s & 1) ? a1[3] : a1[2]) : ((s & 1) ? a1[1] : a1[0]);
      float v2 = (s & 2) ? ((s & 1) ? a2[3] : a2[2]) : ((s & 1) ? a2[1] : a2[0]);
      if (actA) ghsh[0][rr0 * 5 + s] = v0;
      if (s1L0 ? actA : actB) ghs1[rr1 * 5 + s] = v1;
      if (actB) ghsh[1][rr2 * 5 + s] = v2;
    }
    __syncthreads();

    // ---- gates + h_new per layer (128 threads each) ----
    if (tid < 128) {
      if (actA) {
        int bb = tid >> 5, j = tid & 31;
        float ghr = ghsh[0][ j       * 5 + bb] + bsh[0][j];
        float ghz = ghsh[0][(32 + j) * 5 + bb] + bsh[0][32 + j];
        float ghn = ghsh[0][(64 + j) * 5 + bb] + bsh[0][64 + j];
        float rg = fast_sig(gxr + ghr);
        float zg = fast_sig(gxz + ghz);
        float ng = fast_tanh(gxn + rg * ghn);
        float hp = hsh[0][bb][j0 + j];
        float hnew = (1.f - zg) * ng + zg * hp;
        __hip_atomic_store(
            (unsigned*)(histA + ((size_t)(bbase + bb) * T_ + tA) * H_) + j0 + j,
            __float_as_uint(hnew), __ATOMIC_RELAXED, __HIP_MEMORY_SCOPE_AGENT);
      }
    } else if (tid < 256) {
      if (actB) {
        int u = tid - 128, bb = u >> 5, j = u & 31;
        float ghr = ghsh[1][ j       * 5 + bb] + bsh[1][j];
        float ghz = ghsh[1][(32 + j) * 5 + bb] + bsh[1][32 + j];
        float ghn = ghsh[1][(64 + j) * 5 + bb] + bsh[1][64 + j];
        float rg = fast_sig(gxr + ghr);
        float zg = fast_sig(gxz + ghz);
        float ng = fast_tanh(gxn + rg * ghn);
        float hp = hsh[1][bb][j0 + j];
        float hnew = (1.f - zg) * ng + zg * hp;
        __hip_atomic_store(
            (unsigned*)(histB + ((size_t)(bbase + bb) * T_ + tB) * H_) + j0 + j,
            __float_as_uint(hnew), __ATOMIC_RELAXED, __HIP_MEMORY_SCOPE_AGENT);
      }
    }
    __syncthreads();   // protect hsh/ghsh reuse next step (R10: do not remove)
  }
}

// ---------------- sentinel fill: hist rows [t0, t0+tc) for all batches ----
__global__ __launch_bounds__(256) void sent_fill(float* hist, int t0, int tc) {
  int i = blockIdx.x * 256 + threadIdx.x;          // uint4 index
  int per = tc * (H_ >> 2);                        // uint4 per batch
  if (i < B_ * per) {
    int b = i / per, r = i % per;
    uint4* p = (uint4*)(hist + ((size_t)b * T_ + t0) * H_) + r;
    *p = make_uint4(SENT, SENT, SENT, SENT);
  }
}

// ---------------- fp32 -> bf16 hi/lo split ----------------
__device__ __forceinline__ unsigned short f2bf_rne(float f) {
  unsigned u = __float_as_uint(f);
  unsigned r = (u + 0x7fffu + ((u >> 16) & 1u)) >> 16;
  return (unsigned short)r;
}
__device__ __forceinline__ float bf2f(unsigned short h) {
  return __uint_as_float(((unsigned)h) << 16);
}

__global__ __launch_bounds__(256) void conv_split(
    const float* __restrict__ A, int lda, int t0, int tc, int ltc,
    unsigned short* __restrict__ Ah, unsigned short* __restrict__ Al)
{
  int idx = blockIdx.x * 256 + threadIdx.x;
  int m = idx / (lda >> 2), kq = idx % (lda >> 2);
  const float4 v = *(const float4*)
      (A + ((size_t)(m >> ltc) * T_ + t0 + (m & (tc - 1))) * lda + (kq << 2));
  unsigned short h0 = f2bf_rne(v.x), h1 = f2bf_rne(v.y),
                 h2 = f2bf_rne(v.z), h3 = f2bf_rne(v.w);
  unsigned short l0 = f2bf_rne(v.x - bf2f(h0)), l1 = f2bf_rne(v.y - bf2f(h1)),
                 l2 = f2bf_rne(v.z - bf2f(h2)), l3 = f2bf_rne(v.w - bf2f(h3));
  size_t o = (size_t)m * lda + (kq << 2);
  *(ushort4*)(Ah + o) = make_ushort4(h0, h1, h2, h3);
  *(ushort4*)(Al + o) = make_ushort4(l0, l1, l2, l3);
}

// ---------------- split-bf16 MFMA GEMM (double-buffered, pipelined) -------
__global__ __launch_bounds__(256, 2) void gemm_mfma(
    const unsigned short* __restrict__ Ah, const unsigned short* __restrict__ Al,
    const unsigned short* __restrict__ Bh, const unsigned short* __restrict__ Bl,
    const float* __restrict__ bias, float* __restrict__ gxout, int K)
{
  __shared__ unsigned short sAh[2][128 * BKg], sAl[2][128 * BKg];
  __shared__ unsigned short sBh[2][128 * BKg], sBl[2][128 * BKg];

  const int tid = threadIdx.x;
  const int m0 = blockIdx.x << 7, n0 = blockIdx.y << 7;
  const int wave = tid >> 6, lane = tid & 63;
  const int wr = (wave & 1) << 6, wc = (wave >> 1) << 6;
  const int fm = lane & 15, kh = lane >> 4;

  const int srow = tid >> 2, sq = tid & 3;
  const int lofs0 = srow * BKg + (sq << 3);
  const int lofs1 = (64 + srow) * BKg + (sq << 3);

  f32x4 acc[4][4];
  #pragma unroll
  for (int i = 0; i < 4; ++i)
    #pragma unroll
    for (int j = 0; j < 4; ++j)
      acc[i][j] = (f32x4){0.f, 0.f, 0.f, 0.f};

  float4 pAh[2], pAl[2], pBh[2], pBl[2];
  #define PREFETCH(k0)                                                        \
    {                                                                         \
      size_t a0 = (size_t)(m0 + srow) * K + (k0) + (sq << 3);                 \
      size_t a1 = (size_t)(m0 + 64 + srow) * K + (k0) + (sq << 3);            \
      size_t b0 = (size_t)(n0 + srow) * K + (k0) + (sq << 3);                 \
      size_t b1 = (size_t)(n0 + 64 + srow) * K + (k0) + (sq << 3);            \
      pAh[0] = *(const float4*)&Ah[a0]; pAh[1] = *(const float4*)&Ah[a1];     \
      pAl[0] = *(const float4*)&Al[a0]; pAl[1] = *(const float4*)&Al[a1];     \
      pBh[0] = *(const float4*)&Bh[b0]; pBh[1] = *(const float4*)&Bh[b1];     \
      pBl[0] = *(const float4*)&Bl[b0]; pBl[1] = *(const float4*)&Bl[b1];     \
    }
  #define STORE_LDS(buf)                                                      \
    {                                                                         \
      *(float4*)&sAh[buf][lofs0] = pAh[0]; *(float4*)&sAh[buf][lofs1] = pAh[1];\
      *(float4*)&sAl[buf][lofs0] = pAl[0]; *(float4*)&sAl[buf][lofs1] = pAl[1];\
      *(float4*)&sBh[buf][lofs0] = pBh[0]; *(float4*)&sBh[buf][lofs1] = pBh[1];\
      *(float4*)&sBl[buf][lofs0] = pBl[0]; *(float4*)&sBl[buf][lofs1] = pBl[1];\
    }

  PREFETCH(0);
  STORE_LDS(0);
  int buf = 0;

  for (int k0 = 0; k0 < K; k0 += BKg) {
    __syncthreads();
    const bool more = (k0 + BKg) < K;
    if (more) PREFETCH(k0 + BKg);

    short8 fAh[4], fAl[4], fBh[4], fBl[4];
    #pragma unroll
    for (int i = 0; i < 4; ++i) {
      int ao = (wr + i * 16 + fm) * BKg + (kh << 3);
      int bo = (wc + i * 16 + fm) * BKg + (kh << 3);
      fAh[i] = *(const short8*)&sAh[buf][ao];
      fAl[i] = *(const short8*)&sAl[buf][ao];
      fBh[i] = *(const short8*)&sBh[buf][bo];
      fBl[i] = *(const short8*)&sBl[buf][bo];
    }
    #pragma unroll
    for (int i = 0; i < 4; ++i)
      #pragma unroll
      for (int j = 0; j < 4; ++j) {
        acc[i][j] = __builtin_amdgcn_mfma_f32_16x16x32_bf16(
            fAh[i], fBh[j], acc[i][j], 0, 0, 0);
        acc[i][j] = __builtin_amdgcn_mfma_f32_16x16x32_bf16(
            fAh[i], fBl[j], acc[i][j], 0, 0, 0);
        acc[i][j] = __builtin_amdgcn_mfma_f32_16x16x32_bf16(
            fAl[i], fBh[j], acc[i][j], 0, 0, 0);
      }
    if (more) {
      STORE_LDS(buf ^ 1);
      buf ^= 1;
    }
  }

  #pragma unroll
  for (int j = 0; j < 4; ++j) {
    int col = n0 + wc + j * 16 + fm;
    float bv = bias[col];
    #pragma unroll
    for (int i = 0; i < 4; ++i) {
      int rowb = m0 + wr + i * 16 + (kh << 2);
      #pragma unroll
      for (int r = 0; r < 4; ++r)
        gxout[(size_t)(rowb + r) * G3_ + col] = acc[i][j][r] + bv;
    }
  }
}

// ---------------- final FC ----------------
__global__ void fc_kernel(const float* __restrict__ hist, const float* __restrict__ Wfc,
                          const float* __restrict__ bfc, float* __restrict__ out)
{
  int b = blockIdx.x, lane = threadIdx.x;
  const float* h = hist + ((size_t)b*T_ + (T_-1))*H_;
  float acc = 0.f;
  for (int j = lane; j < H_; j += 64) acc += h[j]*Wfc[j];
  #pragma unroll
  for (int off = 32; off; off >>= 1) acc += __shfl_down(acc, off, 64);
  if (lane == 0) out[b] = acc + bfc[0];
}

extern "C" void kernel_launch(void* const* d_in, const int* in_sizes, int n_in,
                              void* d_out, int out_size, void* d_ws, size_t ws_size,
                              hipStream_t stream)
{
  const float* X    = (const float*)d_in[0];
  const float* Wih0 = (const float*)d_in[1];
  const float* Whh0 = (const float*)d_in[2];
  const float* bih0 = (const float*)d_in[3];
  const float* bhh0 = (const float*)d_in[4];
  const float* Wih1 = (const float*)d_in[5];
  const float* Whh1 = (const float*)d_in[6];
  const float* bih1 = (const float*)d_in[7];
  const float* bhh1 = (const float*)d_in[8];
  const float* Wfc  = (const float*)d_in[9];
  const float* bfc  = (const float*)d_in[10];

  const size_t histE = (size_t)B_ * T_ * H_;        // floats
  float* hist1 = (float*)((char*)d_ws + 4096);      // h1 (layer-0 out)
  float* hist2 = hist1 + histE;                     // h2 (layer-1 out)
  char* p = (char*)(hist2 + histE);
  unsigned short* Bh0 = (unsigned short*)p; p += (size_t)G3_ * D0_ * 2;
  unsigned short* Bl0 = (unsigned short*)p; p += (size_t)G3_ * D0_ * 2;
  unsigned short* Bh1 = (unsigned short*)p; p += (size_t)G3_ * H_ * 2;
  unsigned short* Bl1 = (unsigned short*)p; p += (size_t)G3_ * H_ * 2;

  // per-tcg need = 2*gx (B*tcg*G3*4) + 2*A-split (B*tcg*512*2) = B*tcg*14336
  size_t fixed = (size_t)(p - (char*)d_ws);
  int tcg = 16;
  if      (ws_size >= fixed + (size_t)B_ * 64 * 14336) tcg = 64;
  else if (ws_size >= fixed + (size_t)B_ * 32 * 14336) tcg = 32;
  int ltc = 31 - __builtin_clz((unsigned)tcg);

  float* gxL0 = (float*)p; p += (size_t)B_ * tcg * G3_ * 4;
  float* gxL1 = (float*)p; p += (size_t)B_ * tcg * G3_ * 4;
  unsigned short* Ah = (unsigned short*)p; p += (size_t)B_ * tcg * 512 * 2;
  unsigned short* Al = (unsigned short*)p;

  // one-time sentinel fills (each hist row written exactly once -> no refills)
  const int sentGrid = (B_ * T_ * (H_ >> 2) + 255) / 256;
  hipLaunchKernelGGL(sent_fill, dim3(sentGrid), dim3(256), 0, stream,
                     hist1, 0, T_);
  hipLaunchKernelGGL(sent_fill, dim3(sentGrid), dim3(256), 0, stream,
                     hist2, 0, T_);

  // weight splits (once per layer)
  hipLaunchKernelGGL(conv_split, dim3((G3_ * D0_ / 4) / 256), dim3(256), 0,
                     stream, Wih0, D0_, 0, 1 << 30, 30, Bh0, Bl0);
  hipLaunchKernelGGL(conv_split, dim3((G3_ * H_ / 4) / 256), dim3(256), 0,
                     stream, Wih1, H_, 0, 1 << 30, 30, Bh1, Bl1);

  const int nc = T_ / tcg;
  for (int s = 0; s <= nc; ++s) {
    if (s < nc) {   // layer-0 pre-work for chunk s
      hipLaunchKernelGGL(conv_split, dim3((B_ * tcg * (D0_ / 4)) / 256),
                         dim3(256), 0, stream,
                         X, D0_, s * tcg, tcg, ltc, Ah, Al);
      hipLaunchKernelGGL(gemm_mfma, dim3((B_ * tcg) >> 7, G3_ >> 7), dim3(256),
                         0, stream, Ah, Al, Bh0, Bl0, bih0, gxL0, D0_);
    }
    if (s >= 1) {   // layer-1 pre-work for chunk s-1 (h1 chunk complete)
      hipLaunchKernelGGL(conv_split, dim3((B_ * tcg * (H_ / 4)) / 256),
                         dim3(256), 0, stream,
                         (const float*)hist1, H_, (s - 1) * tcg, tcg, ltc,
                         Ah, Al);
      hipLaunchKernelGGL(gemm_mfma, dim3((B_ * tcg) >> 7, G3_ >> 7), dim3(256),
                         0, stream, Ah, Al, Bh1, Bl1, bih1, gxL1, H_);
    }
    const int tcA = (s < nc) ? tcg : 0;
    const int tcB = (s >= 1) ? tcg : 0;
    hipLaunchKernelGGL(scan_fused, dim3(256), dim3(512), 0, stream,
                       Whh0, bhh0, (const float*)gxL0, hist1, s * tcg, tcA,
                       Whh1, bhh1, (const float*)gxL1, hist2, (s - 1) * tcg,
                       tcB);
  }

  hipLaunchKernelGGL(fc_kernel, dim3(64), dim3(64), 0, stream,
                     (const float*)hist2, Wfc, bfc, (float*)d_out);
}

// Round 8
// 3758.471 us; speedup vs baseline: 4.7050x; 1.3018x over previous
//
#include <hip/hip_runtime.h>
#include <math.h>

#define B_  64
#define T_  512
#define D0_ 128
#define H_  512
#define G3_ 1536
#define HSTR 512
#define BKg 32
#define SENT 0x7FC00000u   // NaN sentinel; |h|<1 strictly so real h never matches

typedef short short8 __attribute__((ext_vector_type(8)));
typedef float f32x4 __attribute__((ext_vector_type(4)));
typedef unsigned uint32x4 __attribute__((ext_vector_type(4)));

__device__ __forceinline__ float fast_sig(float x) {
  return __builtin_amdgcn_rcpf(1.f + __expf(-x));
}
__device__ __forceinline__ float fast_tanh(float x) {
  // 1 - 2/(1+e^{2x}); saturates correctly at +/-inf
  return 1.f - 2.f * __builtin_amdgcn_rcpf(1.f + __expf(2.f * x));
}

// ---------------- scan kernel (R1 structure + R17 quad polls, R18 fix) ----
// 256 blocks = 16 groups x 16 blocks; data-as-flag exchange (hist pre-filled
// with SENT; consumers poll h words; producer b32 stores are the signal).
// R11: 768 threads (12 waves), 1 row x 64 k per thread; w[64] in VGPRs.
// FAILED-ATTEMPT LEDGER (do not retry):
//  R12 XCD-colocation: FETCH -57% but dur +4.5% (latency is in the coherence
//      point, not placement). R13 512-block dual-set: poll co-tenancy 2x
//      per-step. R14 s_sleep/pair-store/setprio bundle: +4%. R15 LDS-counter
//      chunk gating: 1.47e9 bank conflicts, 4.7x. R16 same-block dual-layer
//      fusion: compiler caps arch VGPRs at 128 (R4/R9 wall) -> spill, 2.2x.
//  R17 container crash: asm output "=v" WITHOUT early-clobber let the dest
//      tuple alias the address pair -> 2nd poll iteration loads from a
//      clobbered address (fault/hang). FIX (R18): "=&v" early-clobber.
// R17/R18: poll at quad (b128) granularity via inline asm `sc0 sc1` coherent
// loads: 512 loads/pass (threads 0-511) instead of 1024 b64 atomics -- same
// per-word SENT checks (correctness identical), half the coherence-point
// traffic. gx prefetch moved after staging (hides under the dot; avoids the
// asm vmcnt(0) draining it).
// LESSON (R10): do NOT remove the trailing sync / poll early.
__global__ __launch_bounds__(768, 3) void scan_kernel(
    const float* __restrict__ Whh, const float* __restrict__ bhh,
    const float* __restrict__ gx, float* __restrict__ hist,
    int t0, int tc, int gxt0, int gxT)
{
  __shared__ float hsh[4 * HSTR];
  __shared__ float ghsh[96 * 5];
  __shared__ float bsh[96];

  const int tid = threadIdx.x;
  const int blk = blockIdx.x;
  const int g = blk >> 4, c = blk & 15;   // R11 mapping (measured best)
  const int j0 = c << 5;
  const int bbase = g << 2;

  const int r0 = tid >> 3, s = tid & 7;          // 96 rows x 8 k-slices
  const int grow0 = (r0 >> 5) * H_ + j0 + (r0 & 31);

  float w[64];
  {
    const float* R0 = Whh + (size_t)grow0 * H_ + (s << 2);
    #pragma unroll
    for (int kk = 0; kk < 16; ++kk)
      *(float4*)&w[kk * 4] = *(const float4*)(R0 + kk * 32);
  }
  if (tid < 96)
    bsh[tid] = bhh[(tid >> 5) * H_ + j0 + (tid & 31)];

  size_t go0 = 0;
  if (tid < 128) {
    int bb = tid >> 5, j = tid & 31;
    go0 = ((size_t)(bbase + bb) * gxT) * (size_t)G3_ + j0 + j;
  }
  __syncthreads();

  for (int t = t0; t < t0 + tc; ++t) {
    // ---- stage h_prev into LDS ----
    if (t == 0) {
      for (int idx = tid; idx < 2048; idx += 768)
        hsh[(idx >> 9) * HSTR + (idx & 511)] = 0.f;
    } else if (tid < 512) {
      // R17: one b128 coherent load per thread covers 4 words (quad).
      // quad: bb = tid>>7 (batch), e4 = tid&127 (quad-in-row).
      const int bb = tid >> 7, e4 = tid & 127;
      const unsigned* qp = (const unsigned*)
          (hist + ((size_t)(bbase + bb) * T_ + (t - 1)) * H_) + (e4 << 2);
      for (;;) {
        uint32x4 v;
        // R18: "=&v" early-clobber -- dest tuple must NOT alias the address
        // pair (aliasing corrupted the 2nd iteration's address in R17).
        asm volatile(
            "global_load_dwordx4 %0, %1, off sc0 sc1\n\t"
            "s_waitcnt vmcnt(0)"
            : "=&v"(v) : "v"(qp) : "memory");
        if (v.x != SENT && v.y != SENT && v.z != SENT && v.w != SENT) {
          *(float4*)&hsh[bb * HSTR + (e4 << 2)] =
              make_float4(__uint_as_float(v.x), __uint_as_float(v.y),
                          __uint_as_float(v.z), __uint_as_float(v.w));
          break;
        }
      }
    }

    // ---- gx prefetch: issued after polls; latency hides under the dot ----
    float gxr = 0.f, gxz = 0.f, gxn = 0.f;
    if (tid < 128) {
      size_t go = go0 + (size_t)(t - gxt0) * (size_t)G3_;
      gxr = gx[go]; gxz = gx[go + 512]; gxn = gx[go + 1024];
    }
    __syncthreads();

    // ---- dots: 1 row x 4 batches, k-slice of 64 per thread ----
    float acc[4];
    #pragma unroll
    for (int b = 0; b < 4; ++b) {
      const float* hb = hsh + b * HSTR + (s << 2);
      float a0 = 0.f, a1 = 0.f;
      #pragma unroll
      for (int kk = 0; kk < 16; kk += 2) {
        float4 h0 = *(const float4*)(hb + kk * 32);
        float4 h1 = *(const float4*)(hb + kk * 32 + 32);
        a0 += w[kk*4+0]*h0.x; a0 += w[kk*4+1]*h0.y;
        a0 += w[kk*4+2]*h0.z; a0 += w[kk*4+3]*h0.w;
        a1 += w[kk*4+4]*h1.x; a1 += w[kk*4+5]*h1.y;
        a1 += w[kk*4+6]*h1.z; a1 += w[kk*4+7]*h1.w;
      }
      acc[b] = a0 + a1;
    }

    #pragma unroll
    for (int m = 1; m < 8; m <<= 1) {
      #pragma unroll
      for (int b = 0; b < 4; ++b)
        acc[b] += __shfl_xor(acc[b], m, 64);
    }
    if (s < 4) {
      float v = (s & 2) ? ((s & 1) ? acc[3] : acc[2])
                        : ((s & 1) ? acc[1] : acc[0]);
      ghsh[r0 * 5 + s] = v;
    }
    __syncthreads();

    // ---- gates + h_new; fast-math gates (serial critical path) ----
    if (tid < 128) {
      int bb = tid >> 5, j = tid & 31;
      float ghr = ghsh[ j       * 5 + bb] + bsh[j];
      float ghz = ghsh[(32 + j) * 5 + bb] + bsh[32 + j];
      float ghn = ghsh[(64 + j) * 5 + bb] + bsh[64 + j];
      float rg = fast_sig(gxr + ghr);
      float zg = fast_sig(gxz + ghz);
      float ng = fast_tanh(gxn + rg * ghn);
      float hp = hsh[bb * HSTR + j0 + j];
      float hnew = (1.f - zg) * ng + zg * hp;
      __hip_atomic_store(
          (unsigned*)(hist + ((size_t)(bbase + bb) * T_ + t) * H_) + j0 + j,
          __float_as_uint(hnew), __ATOMIC_RELAXED, __HIP_MEMORY_SCOPE_AGENT);
    }
    __syncthreads();   // protect hsh/ghsh reuse next step (R10: do not remove)
  }
}

// ---------------- sentinel fill: hist rows [t0, t0+tc) for all batches ----
__global__ __launch_bounds__(256) void sent_fill(float* hist, int t0, int tc) {
  int i = blockIdx.x * 256 + threadIdx.x;          // uint4 index
  int per = tc * (H_ >> 2);                        // uint4 per batch
  if (i < B_ * per) {
    int b = i / per, r = i % per;
    uint4* p = (uint4*)(hist + ((size_t)b * T_ + t0) * H_) + r;
    *p = make_uint4(SENT, SENT, SENT, SENT);
  }
}

// ---------------- fp32 -> bf16 hi/lo split ----------------
__device__ __forceinline__ unsigned short f2bf_rne(float f) {
  unsigned u = __float_as_uint(f);
  unsigned r = (u + 0x7fffu + ((u >> 16) & 1u)) >> 16;
  return (unsigned short)r;
}
__device__ __forceinline__ float bf2f(unsigned short h) {
  return __uint_as_float(((unsigned)h) << 16);
}

__global__ __launch_bounds__(256) void conv_split(
    const float* __restrict__ A, int lda, int t0, int tc, int ltc,
    unsigned short* __restrict__ Ah, unsigned short* __restrict__ Al)
{
  int idx = blockIdx.x * 256 + threadIdx.x;
  int m = idx / (lda >> 2), kq = idx % (lda >> 2);
  const float4 v = *(const float4*)
      (A + ((size_t)(m >> ltc) * T_ + t0 + (m & (tc - 1))) * lda + (kq << 2));
  unsigned short h0 = f2bf_rne(v.x), h1 = f2bf_rne(v.y),
                 h2 = f2bf_rne(v.z), h3 = f2bf_rne(v.w);
  unsigned short l0 = f2bf_rne(v.x - bf2f(h0)), l1 = f2bf_rne(v.y - bf2f(h1)),
                 l2 = f2bf_rne(v.z - bf2f(h2)), l3 = f2bf_rne(v.w - bf2f(h3));
  size_t o = (size_t)m * lda + (kq << 2);
  *(ushort4*)(Ah + o) = make_ushort4(h0, h1, h2, h3);
  *(ushort4*)(Al + o) = make_ushort4(l0, l1, l2, l3);
}

// ---------------- split-bf16 MFMA GEMM (double-buffered, pipelined) -------
__global__ __launch_bounds__(256, 2) void gemm_mfma(
    const unsigned short* __restrict__ Ah, const unsigned short* __restrict__ Al,
    const unsigned short* __restrict__ Bh, const unsigned short* __restrict__ Bl,
    const float* __restrict__ bias, float* __restrict__ gxout, int K)
{
  __shared__ unsigned short sAh[2][128 * BKg], sAl[2][128 * BKg];
  __shared__ unsigned short sBh[2][128 * BKg], sBl[2][128 * BKg];

  const int tid = threadIdx.x;
  const int m0 = blockIdx.x << 7, n0 = blockIdx.y << 7;
  const int wave = tid >> 6, lane = tid & 63;
  const int wr = (wave & 1) << 6, wc = (wave >> 1) << 6;
  const int fm = lane & 15, kh = lane >> 4;

  const int srow = tid >> 2, sq = tid & 3;
  const int lofs0 = srow * BKg + (sq << 3);
  const int lofs1 = (64 + srow) * BKg + (sq << 3);

  f32x4 acc[4][4];
  #pragma unroll
  for (int i = 0; i < 4; ++i)
    #pragma unroll
    for (int j = 0; j < 4; ++j)
      acc[i][j] = (f32x4){0.f, 0.f, 0.f, 0.f};

  float4 pAh[2], pAl[2], pBh[2], pBl[2];
  #define PREFETCH(k0)                                                        \
    {                                                                         \
      size_t a0 = (size_t)(m0 + srow) * K + (k0) + (sq << 3);                 \
      size_t a1 = (size_t)(m0 + 64 + srow) * K + (k0) + (sq << 3);            \
      size_t b0 = (size_t)(n0 + srow) * K + (k0) + (sq << 3);                 \
      size_t b1 = (size_t)(n0 + 64 + srow) * K + (k0) + (sq << 3);            \
      pAh[0] = *(const float4*)&Ah[a0]; pAh[1] = *(const float4*)&Ah[a1];     \
      pAl[0] = *(const float4*)&Al[a0]; pAl[1] = *(const float4*)&Al[a1];     \
      pBh[0] = *(const float4*)&Bh[b0]; pBh[1] = *(const float4*)&Bh[b1];     \
      pBl[0] = *(const float4*)&Bl[b0]; pBl[1] = *(const float4*)&Bl[b1];     \
    }
  #define STORE_LDS(buf)                                                      \
    {                                                                         \
      *(float4*)&sAh[buf][lofs0] = pAh[0]; *(float4*)&sAh[buf][lofs1] = pAh[1];\
      *(float4*)&sAl[buf][lofs0] = pAl[0]; *(float4*)&sAl[buf][lofs1] = pAl[1];\
      *(float4*)&sBh[buf][lofs0] = pBh[0]; *(float4*)&sBh[buf][lofs1] = pBh[1];\
      *(float4*)&sBl[buf][lofs0] = pBl[0]; *(float4*)&sBl[buf][lofs1] = pBl[1];\
    }

  PREFETCH(0);
  STORE_LDS(0);
  int buf = 0;

  for (int k0 = 0; k0 < K; k0 += BKg) {
    __syncthreads();
    const bool more = (k0 + BKg) < K;
    if (more) PREFETCH(k0 + BKg);

    short8 fAh[4], fAl[4], fBh[4], fBl[4];
    #pragma unroll
    for (int i = 0; i < 4; ++i) {
      int ao = (wr + i * 16 + fm) * BKg + (kh << 3);
      int bo = (wc + i * 16 + fm) * BKg + (kh << 3);
      fAh[i] = *(const short8*)&sAh[buf][ao];
      fAl[i] = *(const short8*)&sAl[buf][ao];
      fBh[i] = *(const short8*)&sBh[buf][bo];
      fBl[i] = *(const short8*)&sBl[buf][bo];
    }
    #pragma unroll
    for (int i = 0; i < 4; ++i)
      #pragma unroll
      for (int j = 0; j < 4; ++j) {
        acc[i][j] = __builtin_amdgcn_mfma_f32_16x16x32_bf16(
            fAh[i], fBh[j], acc[i][j], 0, 0, 0);
        acc[i][j] = __builtin_amdgcn_mfma_f32_16x16x32_bf16(
            fAh[i], fBl[j], acc[i][j], 0, 0, 0);
        acc[i][j] = __builtin_amdgcn_mfma_f32_16x16x32_bf16(
            fAl[i], fBh[j], acc[i][j], 0, 0, 0);
      }
    if (more) {
      STORE_LDS(buf ^ 1);
      buf ^= 1;
    }
  }

  #pragma unroll
  for (int j = 0; j < 4; ++j) {
    int col = n0 + wc + j * 16 + fm;
    float bv = bias[col];
    #pragma unroll
    for (int i = 0; i < 4; ++i) {
      int rowb = m0 + wr + i * 16 + (kh << 2);
      #pragma unroll
      for (int r = 0; r < 4; ++r)
        gxout[(size_t)(rowb + r) * G3_ + col] = acc[i][j][r] + bv;
    }
  }
}

// ---------------- final FC ----------------
__global__ void fc_kernel(const float* __restrict__ hist, const float* __restrict__ Wfc,
                          const float* __restrict__ bfc, float* __restrict__ out)
{
  int b = blockIdx.x, lane = threadIdx.x;
  const float* h = hist + ((size_t)b*T_ + (T_-1))*H_;
  float acc = 0.f;
  for (int j = lane; j < H_; j += 64) acc += h[j]*Wfc[j];
  #pragma unroll
  for (int off = 32; off; off >>= 1) acc += __shfl_down(acc, off, 64);
  if (lane == 0) out[b] = acc + bfc[0];
}

extern "C" void kernel_launch(void* const* d_in, const int* in_sizes, int n_in,
                              void* d_out, int out_size, void* d_ws, size_t ws_size,
                              hipStream_t stream)
{
  const float* X    = (const float*)d_in[0];
  const float* Wih0 = (const float*)d_in[1];
  const float* Whh0 = (const float*)d_in[2];
  const float* bih0 = (const float*)d_in[3];
  const float* bhh0 = (const float*)d_in[4];
  const float* Wih1 = (const float*)d_in[5];
  const float* Whh1 = (const float*)d_in[6];
  const float* bih1 = (const float*)d_in[7];
  const float* bhh1 = (const float*)d_in[8];
  const float* Wfc  = (const float*)d_in[9];
  const float* bfc  = (const float*)d_in[10];

  float* hist = (float*)((char*)d_ws + 4096);
  const size_t histB = (size_t)B_*T_*H_*4;

  const size_t bB = (size_t)G3_ * 512 * 2;
  int tcg = 128;
  {
    size_t fixed = 4096 + histB + 2 * bB;
    if      (ws_size >= fixed + (size_t)B_*512*((size_t)G3_*4 + 512*4)) tcg = 512;
    else if (ws_size >= fixed + (size_t)B_*256*((size_t)G3_*4 + 512*4)) tcg = 256;
  }
  int ltc = 31 - __builtin_clz((unsigned)tcg);

  float* gxbuf = (float*)((char*)d_ws + 4096 + histB);
  const size_t gxB = (size_t)B_*tcg*G3_*4;
  unsigned short* Ahb = (unsigned short*)((char*)gxbuf + gxB);
  const size_t aB = (size_t)B_*tcg*512*2;
  unsigned short* Alb = (unsigned short*)((char*)Ahb + aB);
  unsigned short* Bhb = (unsigned short*)((char*)Alb + aB);
  unsigned short* Blb = (unsigned short*)((char*)Bhb + bB);

  const int sentGridFull = (B_ * T_ * (H_ >> 2) + 255) / 256;
  const int sentGridChunk = (B_ * tcg * (H_ >> 2) + 255) / 256;

  // layer 0: whole hist -> sentinel before its first scan (conv/gemm read X)
  hipLaunchKernelGGL(sent_fill, dim3(sentGridFull), dim3(256), 0, stream,
                     hist, 0, T_);

  for (int lay = 0; lay < 2; ++lay) {
    const float* A   = lay ? (const float*)hist : X;
    int lda          = lay ? H_ : D0_;
    const float* Wih = lay ? Wih1 : Wih0;
    const float* bih = lay ? bih1 : bih0;
    const float* Whh = lay ? Whh1 : Whh0;
    const float* bhh = lay ? bhh1 : bhh0;

    hipLaunchKernelGGL(conv_split, dim3((G3_*lda/4)/256), dim3(256), 0, stream,
                       Wih, lda, 0, 1 << 30, 30, Bhb, Blb);

    for (int t0g = 0; t0g < T_; t0g += tcg) {
      int M = B_ * tcg;
      // conv reads this chunk's hist rows (layer 1) BEFORE they're sentineled
      hipLaunchKernelGGL(conv_split, dim3((M*lda/4)/256), dim3(256), 0, stream,
                         A, lda, t0g, tcg, ltc, Ahb, Alb);
      if (lay == 1)   // re-sentinel the rows this chunk's scan will write
        hipLaunchKernelGGL(sent_fill, dim3(sentGridChunk), dim3(256), 0, stream,
                           hist, t0g, tcg);
      dim3 ggrid(M >> 7, G3_ >> 7);
      hipLaunchKernelGGL(gemm_mfma, ggrid, dim3(256), 0, stream,
                         Ahb, Alb, Bhb, Blb, bih, gxbuf, lda);
      hipLaunchKernelGGL(scan_kernel, dim3(256), dim3(768), 0, stream,
                         Whh, bhh, (const float*)gxbuf, hist, t0g, tcg, t0g, tcg);
    }
  }

  hipLaunchKernelGGL(fc_kernel, dim3(64), dim3(64), 0, stream,
                     (const float*)hist, Wfc, bfc, (float*)d_out);
}

// Round 9
// 2710.928 us; speedup vs baseline: 6.5231x; 1.3864x over previous
//
#include <hip/hip_runtime.h>
#include <math.h>

#define B_  64
#define T_  512
#define D0_ 128
#define H_  512
#define G3_ 1536
#define HSTR 512
#define BSTR 528          // bf16-h LDS batch stride (bank-spread: 2-way max)
#define BKg 32
#define SENT 0x7FC00000u   // NaN sentinel; |h|<1 strictly so real h never matches

typedef short short8 __attribute__((ext_vector_type(8)));
typedef float f32x4 __attribute__((ext_vector_type(4)));
typedef unsigned uint32x4 __attribute__((ext_vector_type(4)));

__device__ __forceinline__ float fast_sig(float x) {
  return __builtin_amdgcn_rcpf(1.f + __expf(-x));
}
__device__ __forceinline__ float fast_tanh(float x) {
  // 1 - 2/(1+e^{2x}); saturates correctly at +/-inf
  return 1.f - 2.f * __builtin_amdgcn_rcpf(1.f + __expf(2.f * x));
}

// ---------------- fp32 -> bf16 hi/lo split ----------------
__device__ __forceinline__ unsigned short f2bf_rne(float f) {
  unsigned u = __float_as_uint(f);
  unsigned r = (u + 0x7fffu + ((u >> 16) & 1u)) >> 16;
  return (unsigned short)r;
}
__device__ __forceinline__ float bf2f(unsigned short h) {
  return __uint_as_float(((unsigned)h) << 16);
}

// ---------------- scan kernel (R1 exchange + R19 MFMA dot) ----------------
// 256 blocks = 16 groups x 16 blocks; data-as-flag exchange (hist pre-filled
// with SENT; consumers poll h words; producer b32 stores are the signal).
// 768 threads (12 waves).
// FAILED-ATTEMPT LEDGER (do not retry):
//  R12 XCD-colocation: FETCH -57%, dur +4.5% (latency is the coherence RTT).
//  R13 512-block dual-set: poll co-tenancy 2x per-step. R14 s_sleep/pair-
//  store/setprio: +4%. R15 LDS-counter gating: 1.47e9 bank conflicts, 4.7x.
//  R16 same-block dual-layer fusion: 128-VGPR compiler cap -> spill, 2.2x.
//  R17 asm "=v" w/o early-clobber: dest aliased addr pair -> crash; R18
//  "=&v" fix passed; quad-poll itself NULL (detect RTT-pinned).
// R19: the dot (VALU FMA 1536cy + 768 ds_read_b128 + shfl reduce, serial
// between barriers) moves to matrix cores: gh[96x4] = Whh[96x512] @ h[512x4]
// per block via mfma_f32_16x16x32_bf16, split-bf16 4-product (Wh*hh + Wh*hl
// + Wl*hh + Wl*hl ~= fp32, err ~2^-24; recurrence-safe). 12 waves = 6 M-tiles
// x 2 K-halves, W frags in regs (64 VGPR bf16 = same budget as old w[64]);
// K-half partials in LDS, summed by gate threads (replaces shfl reduce).
// Whh pre-split once per layer by conv_split. Staging converts polled fp32
// h -> bf16 hi/lo into LDS (few VALU ops/thread).
// LESSON (R10): do NOT remove the trailing sync / poll early.
__global__ __launch_bounds__(768, 3) void scan_kernel(
    const unsigned short* __restrict__ WhH, const unsigned short* __restrict__ WhL,
    const float* __restrict__ bhh,
    const float* __restrict__ gx, float* __restrict__ hist,
    int t0, int tc, int gxt0, int gxT)
{
  __shared__ float hsh[4 * HSTR];              // fp32 h_prev (for hp in gates)
  __shared__ unsigned short hbh[4 * BSTR];     // h_prev bf16 hi
  __shared__ unsigned short hbl[4 * BSTR];     // h_prev bf16 lo
  __shared__ float ghp[2][96 * 5];             // per-K-half gh partials
  __shared__ float bsh[96];

  const int tid = threadIdx.x;
  const int blk = blockIdx.x;
  const int g = blk >> 4, c = blk & 15;   // R11 mapping (measured best)
  const int j0 = c << 5;
  const int bbase = g << 2;

  const int wv = tid >> 6, lane = tid & 63;
  const int mtile = wv >> 1, half = wv & 1;     // 6 M-tiles x 2 K-halves
  const int rloc = lane & 15, kq = lane >> 4;   // A-row-in-tile, k-subgroup
  const int row = mtile * 16 + rloc;            // 0..95 (3 gates x 32 cols)
  const int wrow = (row >> 5) * H_ + j0 + (row & 31);

  // W fragments: 8 chunks of K=32 within this wave's K-half; bf16 hi+lo.
  short8 wh[8], wl[8];
  {
    const unsigned short* RH = WhH + (size_t)wrow * H_ + half * 256 + (kq << 3);
    const unsigned short* RL = WhL + (size_t)wrow * H_ + half * 256 + (kq << 3);
    #pragma unroll
    for (int cc = 0; cc < 8; ++cc) {
      wh[cc] = *(const short8*)(RH + cc * 32);
      wl[cc] = *(const short8*)(RL + cc * 32);
    }
  }
  if (tid < 96)
    bsh[tid] = bhh[(tid >> 5) * H_ + j0 + (tid & 31)];

  size_t go0 = 0;
  if (tid < 128) {
    int bb = tid >> 5, j = tid & 31;
    go0 = ((size_t)(bbase + bb) * gxT) * (size_t)G3_ + j0 + j;
  }
  __syncthreads();

  for (int t = t0; t < t0 + tc; ++t) {
    // ---- stage h_prev into LDS (fp32 + bf16 hi/lo) ----
    if (t == 0) {
      for (int idx = tid; idx < 2048; idx += 768) hsh[idx] = 0.f;
      for (int idx = tid; idx < 4 * BSTR; idx += 768) {
        hbh[idx] = 0; hbl[idx] = 0;
      }
    } else if (tid < 512) {
      // one b128 coherent load per thread covers a quad of h words
      const int bb = tid >> 7, e4 = tid & 127;
      const unsigned* qp = (const unsigned*)
          (hist + ((size_t)(bbase + bb) * T_ + (t - 1)) * H_) + (e4 << 2);
      uint32x4 v;
      for (;;) {
        // "=&v" early-clobber: dest must NOT alias addr pair (R17 crash)
        asm volatile(
            "global_load_dwordx4 %0, %1, off sc0 sc1\n\t"
            "s_waitcnt vmcnt(0)"
            : "=&v"(v) : "v"(qp) : "memory");
        if (v.x != SENT && v.y != SENT && v.z != SENT && v.w != SENT) break;
      }
      float4 f = make_float4(__uint_as_float(v.x), __uint_as_float(v.y),
                             __uint_as_float(v.z), __uint_as_float(v.w));
      *(float4*)&hsh[bb * HSTR + (e4 << 2)] = f;
      unsigned short h0 = f2bf_rne(f.x), h1 = f2bf_rne(f.y),
                     h2 = f2bf_rne(f.z), h3 = f2bf_rne(f.w);
      *(ushort4*)&hbh[bb * BSTR + (e4 << 2)] = make_ushort4(h0, h1, h2, h3);
      unsigned short l0 = f2bf_rne(f.x - bf2f(h0)), l1 = f2bf_rne(f.y - bf2f(h1)),
                     l2 = f2bf_rne(f.z - bf2f(h2)), l3 = f2bf_rne(f.w - bf2f(h3));
      *(ushort4*)&hbl[bb * BSTR + (e4 << 2)] = make_ushort4(l0, l1, l2, l3);
    }

    // ---- gx prefetch: after polls; latency hides under the dot ----
    float gxr = 0.f, gxz = 0.f, gxn = 0.f;
    if (tid < 128) {
      size_t go = go0 + (size_t)(t - gxt0) * (size_t)G3_;
      gxr = gx[go]; gxz = gx[go + 512]; gxn = gx[go + 1024];
    }
    __syncthreads();

    // ---- MFMA dot: D[16x16] tile, cols = batches (0-3 valid, rest dup) ----
    {
      f32x4 acc = (f32x4){0.f, 0.f, 0.f, 0.f};
      const int bb4 = lane & 3;   // batch for this B-col (cols 4-15 duplicate)
      const unsigned short* bhp = hbh + bb4 * BSTR + half * 256 + (kq << 3);
      const unsigned short* blp = hbl + bb4 * BSTR + half * 256 + (kq << 3);
      #pragma unroll
      for (int cc = 0; cc < 8; ++cc) {
        short8 bh = *(const short8*)(bhp + cc * 32);
        short8 bl = *(const short8*)(blp + cc * 32);
        acc = __builtin_amdgcn_mfma_f32_16x16x32_bf16(wh[cc], bh, acc, 0, 0, 0);
        acc = __builtin_amdgcn_mfma_f32_16x16x32_bf16(wh[cc], bl, acc, 0, 0, 0);
        acc = __builtin_amdgcn_mfma_f32_16x16x32_bf16(wl[cc], bh, acc, 0, 0, 0);
        acc = __builtin_amdgcn_mfma_f32_16x16x32_bf16(wl[cc], bl, acc, 0, 0, 0);
      }
      // D layout: col = lane&15, row = (lane>>4)*4 + reg. Keep cols 0-3.
      if (rloc < 4) {
        #pragma unroll
        for (int r = 0; r < 4; ++r)
          ghp[half][(mtile * 16 + (kq << 2) + r) * 5 + rloc] = acc[r];
      }
    }
    __syncthreads();

    // ---- gates + h_new; fast-math gates (serial critical path) ----
    if (tid < 128) {
      int bb = tid >> 5, j = tid & 31;
      float ghr = ghp[0][ j       * 5 + bb] + ghp[1][ j       * 5 + bb] + bsh[j];
      float ghz = ghp[0][(32 + j) * 5 + bb] + ghp[1][(32 + j) * 5 + bb] + bsh[32 + j];
      float ghn = ghp[0][(64 + j) * 5 + bb] + ghp[1][(64 + j) * 5 + bb] + bsh[64 + j];
      float rg = fast_sig(gxr + ghr);
      float zg = fast_sig(gxz + ghz);
      float ng = fast_tanh(gxn + rg * ghn);
      float hp = hsh[bb * HSTR + j0 + j];
      float hnew = (1.f - zg) * ng + zg * hp;
      __hip_atomic_store(
          (unsigned*)(hist + ((size_t)(bbase + bb) * T_ + t) * H_) + j0 + j,
          __float_as_uint(hnew), __ATOMIC_RELAXED, __HIP_MEMORY_SCOPE_AGENT);
    }
    __syncthreads();   // protect hsh/ghp reuse next step (R10: do not remove)
  }
}

// ---------------- sentinel fill: hist rows [t0, t0+tc) for all batches ----
__global__ __launch_bounds__(256) void sent_fill(float* hist, int t0, int tc) {
  int i = blockIdx.x * 256 + threadIdx.x;          // uint4 index
  int per = tc * (H_ >> 2);                        // uint4 per batch
  if (i < B_ * per) {
    int b = i / per, r = i % per;
    uint4* p = (uint4*)(hist + ((size_t)b * T_ + t0) * H_) + r;
    *p = make_uint4(SENT, SENT, SENT, SENT);
  }
}

__global__ __launch_bounds__(256) void conv_split(
    const float* __restrict__ A, int lda, int t0, int tc, int ltc,
    unsigned short* __restrict__ Ah, unsigned short* __restrict__ Al)
{
  int idx = blockIdx.x * 256 + threadIdx.x;
  int m = idx / (lda >> 2), kq = idx % (lda >> 2);
  const float4 v = *(const float4*)
      (A + ((size_t)(m >> ltc) * T_ + t0 + (m & (tc - 1))) * lda + (kq << 2));
  unsigned short h0 = f2bf_rne(v.x), h1 = f2bf_rne(v.y),
                 h2 = f2bf_rne(v.z), h3 = f2bf_rne(v.w);
  unsigned short l0 = f2bf_rne(v.x - bf2f(h0)), l1 = f2bf_rne(v.y - bf2f(h1)),
                 l2 = f2bf_rne(v.z - bf2f(h2)), l3 = f2bf_rne(v.w - bf2f(h3));
  size_t o = (size_t)m * lda + (kq << 2);
  *(ushort4*)(Ah + o) = make_ushort4(h0, h1, h2, h3);
  *(ushort4*)(Al + o) = make_ushort4(l0, l1, l2, l3);
}

// ---------------- split-bf16 MFMA GEMM (double-buffered, pipelined) -------
__global__ __launch_bounds__(256, 2) void gemm_mfma(
    const unsigned short* __restrict__ Ah, const unsigned short* __restrict__ Al,
    const unsigned short* __restrict__ Bh, const unsigned short* __restrict__ Bl,
    const float* __restrict__ bias, float* __restrict__ gxout, int K)
{
  __shared__ unsigned short sAh[2][128 * BKg], sAl[2][128 * BKg];
  __shared__ unsigned short sBh[2][128 * BKg], sBl[2][128 * BKg];

  const int tid = threadIdx.x;
  const int m0 = blockIdx.x << 7, n0 = blockIdx.y << 7;
  const int wave = tid >> 6, lane = tid & 63;
  const int wr = (wave & 1) << 6, wc = (wave >> 1) << 6;
  const int fm = lane & 15, kh = lane >> 4;

  const int srow = tid >> 2, sq = tid & 3;
  const int lofs0 = srow * BKg + (sq << 3);
  const int lofs1 = (64 + srow) * BKg + (sq << 3);

  f32x4 acc[4][4];
  #pragma unroll
  for (int i = 0; i < 4; ++i)
    #pragma unroll
    for (int j = 0; j < 4; ++j)
      acc[i][j] = (f32x4){0.f, 0.f, 0.f, 0.f};

  float4 pAh[2], pAl[2], pBh[2], pBl[2];
  #define PREFETCH(k0)                                                        \
    {                                                                         \
      size_t a0 = (size_t)(m0 + srow) * K + (k0) + (sq << 3);                 \
      size_t a1 = (size_t)(m0 + 64 + srow) * K + (k0) + (sq << 3);            \
      size_t b0 = (size_t)(n0 + srow) * K + (k0) + (sq << 3);                 \
      size_t b1 = (size_t)(n0 + 64 + srow) * K + (k0) + (sq << 3);            \
      pAh[0] = *(const float4*)&Ah[a0]; pAh[1] = *(const float4*)&Ah[a1];     \
      pAl[0] = *(const float4*)&Al[a0]; pAl[1] = *(const float4*)&Al[a1];     \
      pBh[0] = *(const float4*)&Bh[b0]; pBh[1] = *(const float4*)&Bh[b1];     \
      pBl[0] = *(const float4*)&Bl[b0]; pBl[1] = *(const float4*)&Bl[b1];     \
    }
  #define STORE_LDS(buf)                                                      \
    {                                                                         \
      *(float4*)&sAh[buf][lofs0] = pAh[0]; *(float4*)&sAh[buf][lofs1] = pAh[1];\
      *(float4*)&sAl[buf][lofs0] = pAl[0]; *(float4*)&sAl[buf][lofs1] = pAl[1];\
      *(float4*)&sBh[buf][lofs0] = pBh[0]; *(float4*)&sBh[buf][lofs1] = pBh[1];\
      *(float4*)&sBl[buf][lofs0] = pBl[0]; *(float4*)&sBl[buf][lofs1] = pBl[1];\
    }

  PREFETCH(0);
  STORE_LDS(0);
  int buf = 0;

  for (int k0 = 0; k0 < K; k0 += BKg) {
    __syncthreads();
    const bool more = (k0 + BKg) < K;
    if (more) PREFETCH(k0 + BKg);

    short8 fAh[4], fAl[4], fBh[4], fBl[4];
    #pragma unroll
    for (int i = 0; i < 4; ++i) {
      int ao = (wr + i * 16 + fm) * BKg + (kh << 3);
      int bo = (wc + i * 16 + fm) * BKg + (kh << 3);
      fAh[i] = *(const short8*)&sAh[buf][ao];
      fAl[i] = *(const short8*)&sAl[buf][ao];
      fBh[i] = *(const short8*)&sBh[buf][bo];
      fBl[i] = *(const short8*)&sBl[buf][bo];
    }
    #pragma unroll
    for (int i = 0; i < 4; ++i)
      #pragma unroll
      for (int j = 0; j < 4; ++j) {
        acc[i][j] = __builtin_amdgcn_mfma_f32_16x16x32_bf16(
            fAh[i], fBh[j], acc[i][j], 0, 0, 0);
        acc[i][j] = __builtin_amdgcn_mfma_f32_16x16x32_bf16(
            fAh[i], fBl[j], acc[i][j], 0, 0, 0);
        acc[i][j] = __builtin_amdgcn_mfma_f32_16x16x32_bf16(
            fAl[i], fBh[j], acc[i][j], 0, 0, 0);
      }
    if (more) {
      STORE_LDS(buf ^ 1);
      buf ^= 1;
    }
  }

  #pragma unroll
  for (int j = 0; j < 4; ++j) {
    int col = n0 + wc + j * 16 + fm;
    float bv = bias[col];
    #pragma unroll
    for (int i = 0; i < 4; ++i) {
      int rowb = m0 + wr + i * 16 + (kh << 2);
      #pragma unroll
      for (int r = 0; r < 4; ++r)
        gxout[(size_t)(rowb + r) * G3_ + col] = acc[i][j][r] + bv;
    }
  }
}

// ---------------- final FC ----------------
__global__ void fc_kernel(const float* __restrict__ hist, const float* __restrict__ Wfc,
                          const float* __restrict__ bfc, float* __restrict__ out)
{
  int b = blockIdx.x, lane = threadIdx.x;
  const float* h = hist + ((size_t)b*T_ + (T_-1))*H_;
  float acc = 0.f;
  for (int j = lane; j < H_; j += 64) acc += h[j]*Wfc[j];
  #pragma unroll
  for (int off = 32; off; off >>= 1) acc += __shfl_down(acc, off, 64);
  if (lane == 0) out[b] = acc + bfc[0];
}

extern "C" void kernel_launch(void* const* d_in, const int* in_sizes, int n_in,
                              void* d_out, int out_size, void* d_ws, size_t ws_size,
                              hipStream_t stream)
{
  const float* X    = (const float*)d_in[0];
  const float* Wih0 = (const float*)d_in[1];
  const float* Whh0 = (const float*)d_in[2];
  const float* bih0 = (const float*)d_in[3];
  const float* bhh0 = (const float*)d_in[4];
  const float* Wih1 = (const float*)d_in[5];
  const float* Whh1 = (const float*)d_in[6];
  const float* bih1 = (const float*)d_in[7];
  const float* bhh1 = (const float*)d_in[8];
  const float* Wfc  = (const float*)d_in[9];
  const float* bfc  = (const float*)d_in[10];

  float* hist = (float*)((char*)d_ws + 4096);
  const size_t histB = (size_t)B_*T_*H_*4;

  const size_t bB = (size_t)G3_ * 512 * 2;   // Wih split (hi or lo)
  const size_t wB = (size_t)G3_ * H_ * 2;    // Whh split (hi or lo)
  int tcg = 128;
  {
    size_t fixed = 4096 + histB + 2 * bB + 2 * wB;
    if      (ws_size >= fixed + (size_t)B_*512*((size_t)G3_*4 + 512*4)) tcg = 512;
    else if (ws_size >= fixed + (size_t)B_*256*((size_t)G3_*4 + 512*4)) tcg = 256;
  }
  int ltc = 31 - __builtin_clz((unsigned)tcg);

  float* gxbuf = (float*)((char*)d_ws + 4096 + histB);
  const size_t gxB = (size_t)B_*tcg*G3_*4;
  unsigned short* Ahb = (unsigned short*)((char*)gxbuf + gxB);
  const size_t aB = (size_t)B_*tcg*512*2;
  unsigned short* Alb = (unsigned short*)((char*)Ahb + aB);
  unsigned short* Bhb = (unsigned short*)((char*)Alb + aB);
  unsigned short* Blb = (unsigned short*)((char*)Bhb + bB);
  unsigned short* Whb = (unsigned short*)((char*)Blb + bB);
  unsigned short* Wlb = (unsigned short*)((char*)Whb + wB);

  const int sentGridFull = (B_ * T_ * (H_ >> 2) + 255) / 256;
  const int sentGridChunk = (B_ * tcg * (H_ >> 2) + 255) / 256;

  // layer 0: whole hist -> sentinel before its first scan (conv/gemm read X)
  hipLaunchKernelGGL(sent_fill, dim3(sentGridFull), dim3(256), 0, stream,
                     hist, 0, T_);

  for (int lay = 0; lay < 2; ++lay) {
    const float* A   = lay ? (const float*)hist : X;
    int lda          = lay ? H_ : D0_;
    const float* Wih = lay ? Wih1 : Wih0;
    const float* bih = lay ? bih1 : bih0;
    const float* Whh = lay ? Whh1 : Whh0;
    const float* bhh = lay ? bhh1 : bhh0;

    hipLaunchKernelGGL(conv_split, dim3((G3_*lda/4)/256), dim3(256), 0, stream,
                       Wih, lda, 0, 1 << 30, 30, Bhb, Blb);
    // Whh -> bf16 hi/lo for the scan's MFMA dot (R19)
    hipLaunchKernelGGL(conv_split, dim3((G3_*H_/4)/256), dim3(256), 0, stream,
                       Whh, H_, 0, 1 << 30, 30, Whb, Wlb);

    for (int t0g = 0; t0g < T_; t0g += tcg) {
      int M = B_ * tcg;
      // conv reads this chunk's hist rows (layer 1) BEFORE they're sentineled
      hipLaunchKernelGGL(conv_split, dim3((M*lda/4)/256), dim3(256), 0, stream,
                         A, lda, t0g, tcg, ltc, Ahb, Alb);
      if (lay == 1)   // re-sentinel the rows this chunk's scan will write
        hipLaunchKernelGGL(sent_fill, dim3(sentGridChunk), dim3(256), 0, stream,
                           hist, t0g, tcg);
      dim3 ggrid(M >> 7, G3_ >> 7);
      hipLaunchKernelGGL(gemm_mfma, ggrid, dim3(256), 0, stream,
                         Ahb, Alb, Bhb, Blb, bih, gxbuf, lda);
      hipLaunchKernelGGL(scan_kernel, dim3(256), dim3(768), 0, stream,
                         Whb, Wlb, bhh, (const float*)gxbuf, hist,
                         t0g, tcg, t0g, tcg);
    }
  }

  hipLaunchKernelGGL(fc_kernel, dim3(64), dim3(64), 0, stream,
                     (const float*)hist, Wfc, bfc, (float*)d_out);
}

// Round 10
// 2568.470 us; speedup vs baseline: 6.8849x; 1.0555x over previous
//
#include <hip/hip_runtime.h>
#include <math.h>

#define B_  64
#define T_  512
#define D0_ 128
#define H_  512
#define G3_ 1536
#define HSTR 512
#define BSTR 528          // bf16-h LDS batch stride (bank-spread: 2-way max)
#define BKg 32
#define SENT 0x7FC00000u   // NaN sentinel; |h|<1 strictly so real h never matches

typedef short short8 __attribute__((ext_vector_type(8)));
typedef float f32x4 __attribute__((ext_vector_type(4)));
typedef unsigned uint32x4 __attribute__((ext_vector_type(4)));

__device__ __forceinline__ float fast_sig(float x) {
  return __builtin_amdgcn_rcpf(1.f + __expf(-x));
}
__device__ __forceinline__ float fast_tanh(float x) {
  // 1 - 2/(1+e^{2x}); saturates correctly at +/-inf
  return 1.f - 2.f * __builtin_amdgcn_rcpf(1.f + __expf(2.f * x));
}

// ---------------- fp32 -> bf16 hi/lo split ----------------
__device__ __forceinline__ unsigned short f2bf_rne(float f) {
  unsigned u = __float_as_uint(f);
  unsigned r = (u + 0x7fffu + ((u >> 16) & 1u)) >> 16;
  return (unsigned short)r;
}
__device__ __forceinline__ float bf2f(unsigned short h) {
  return __uint_as_float(((unsigned)h) << 16);
}

// ---------------- scan kernel (R1 exchange + R19 MFMA dot + R20) ----------
// 256 blocks = 16 groups x 16 blocks; data-as-flag exchange (hist pre-filled
// with SENT; consumers poll h words; producer b32 stores are the signal).
// 768 threads (12 waves).
// FAILED-ATTEMPT LEDGER (do not retry):
//  R12 XCD-colocation: FETCH -57%, dur +4.5% (latency is the coherence RTT).
//  R13 512-block dual-set: poll co-tenancy 2x per-step. R14 s_sleep/pair-
//  store/setprio: +4%. R15 LDS-counter gating: 1.47e9 bank conflicts, 4.7x.
//  R16 same-block dual-layer fusion: 128-VGPR compiler cap -> spill, 2.2x.
//  R17 asm "=v" w/o early-clobber: dest aliased addr pair -> crash; R18
//  "=&v" fix passed; quad-poll itself NULL (detect RTT-pinned).
// R19 WIN (866 -> 568 us scan): gh[96x4] = Whh @ h via
// mfma_f32_16x16x32_bf16 split-bf16; 12 waves = 6 M-tiles x 2 K-halves,
// W frags in regs; K-half partials in LDS summed by gate threads.
// R20: (a) 3 independent accumulators (one per product class) -- the R19
// single-acc chain serialized 32 dependent MFMAs (MfmaUtil 30% vs ~9%
// theoretical issue = latency-stalled); chain 32 -> 8, phase issue-bound.
// (b) drop Wl*hl product (<=2^-16 relative, same 3-product scheme as the
// passing gemm_mfma): 24 MFMA/wave.
// LESSON (R10): do NOT remove the trailing sync / poll early.
__global__ __launch_bounds__(768, 3) void scan_kernel(
    const unsigned short* __restrict__ WhH, const unsigned short* __restrict__ WhL,
    const float* __restrict__ bhh,
    const float* __restrict__ gx, float* __restrict__ hist,
    int t0, int tc, int gxt0, int gxT)
{
  __shared__ float hsh[4 * HSTR];              // fp32 h_prev (for hp in gates)
  __shared__ unsigned short hbh[4 * BSTR];     // h_prev bf16 hi
  __shared__ unsigned short hbl[4 * BSTR];     // h_prev bf16 lo
  __shared__ float ghp[2][96 * 5];             // per-K-half gh partials
  __shared__ float bsh[96];

  const int tid = threadIdx.x;
  const int blk = blockIdx.x;
  const int g = blk >> 4, c = blk & 15;   // R11 mapping (measured best)
  const int j0 = c << 5;
  const int bbase = g << 2;

  const int wv = tid >> 6, lane = tid & 63;
  const int mtile = wv >> 1, half = wv & 1;     // 6 M-tiles x 2 K-halves
  const int rloc = lane & 15, kq = lane >> 4;   // A-row-in-tile, k-subgroup
  const int row = mtile * 16 + rloc;            // 0..95 (3 gates x 32 cols)
  const int wrow = (row >> 5) * H_ + j0 + (row & 31);

  // W fragments: 8 chunks of K=32 within this wave's K-half; bf16 hi+lo.
  short8 wh[8], wl[8];
  {
    const unsigned short* RH = WhH + (size_t)wrow * H_ + half * 256 + (kq << 3);
    const unsigned short* RL = WhL + (size_t)wrow * H_ + half * 256 + (kq << 3);
    #pragma unroll
    for (int cc = 0; cc < 8; ++cc) {
      wh[cc] = *(const short8*)(RH + cc * 32);
      wl[cc] = *(const short8*)(RL + cc * 32);
    }
  }
  if (tid < 96)
    bsh[tid] = bhh[(tid >> 5) * H_ + j0 + (tid & 31)];

  size_t go0 = 0;
  if (tid < 128) {
    int bb = tid >> 5, j = tid & 31;
    go0 = ((size_t)(bbase + bb) * gxT) * (size_t)G3_ + j0 + j;
  }
  __syncthreads();

  for (int t = t0; t < t0 + tc; ++t) {
    // ---- stage h_prev into LDS (fp32 + bf16 hi/lo) ----
    if (t == 0) {
      for (int idx = tid; idx < 2048; idx += 768) hsh[idx] = 0.f;
      for (int idx = tid; idx < 4 * BSTR; idx += 768) {
        hbh[idx] = 0; hbl[idx] = 0;
      }
    } else if (tid < 512) {
      // one b128 coherent load per thread covers a quad of h words
      const int bb = tid >> 7, e4 = tid & 127;
      const unsigned* qp = (const unsigned*)
          (hist + ((size_t)(bbase + bb) * T_ + (t - 1)) * H_) + (e4 << 2);
      uint32x4 v;
      for (;;) {
        // "=&v" early-clobber: dest must NOT alias addr pair (R17 crash)
        asm volatile(
            "global_load_dwordx4 %0, %1, off sc0 sc1\n\t"
            "s_waitcnt vmcnt(0)"
            : "=&v"(v) : "v"(qp) : "memory");
        if (v.x != SENT && v.y != SENT && v.z != SENT && v.w != SENT) break;
      }
      float4 f = make_float4(__uint_as_float(v.x), __uint_as_float(v.y),
                             __uint_as_float(v.z), __uint_as_float(v.w));
      *(float4*)&hsh[bb * HSTR + (e4 << 2)] = f;
      unsigned short h0 = f2bf_rne(f.x), h1 = f2bf_rne(f.y),
                     h2 = f2bf_rne(f.z), h3 = f2bf_rne(f.w);
      *(ushort4*)&hbh[bb * BSTR + (e4 << 2)] = make_ushort4(h0, h1, h2, h3);
      unsigned short l0 = f2bf_rne(f.x - bf2f(h0)), l1 = f2bf_rne(f.y - bf2f(h1)),
                     l2 = f2bf_rne(f.z - bf2f(h2)), l3 = f2bf_rne(f.w - bf2f(h3));
      *(ushort4*)&hbl[bb * BSTR + (e4 << 2)] = make_ushort4(l0, l1, l2, l3);
    }

    // ---- gx prefetch: after polls; latency hides under the dot ----
    float gxr = 0.f, gxz = 0.f, gxn = 0.f;
    if (tid < 128) {
      size_t go = go0 + (size_t)(t - gxt0) * (size_t)G3_;
      gxr = gx[go]; gxz = gx[go + 512]; gxn = gx[go + 1024];
    }
    __syncthreads();

    // ---- MFMA dot: D[16x16] tile, cols = batches (0-3 valid, rest dup) ----
    {
      // R20: 3 independent acc chains (len 8) instead of 1 chain of 32;
      // Wl*hl dropped (<=2^-16 rel; matches gemm_mfma's 3-product scheme).
      f32x4 aHH = (f32x4){0.f, 0.f, 0.f, 0.f};
      f32x4 aHL = (f32x4){0.f, 0.f, 0.f, 0.f};
      f32x4 aLH = (f32x4){0.f, 0.f, 0.f, 0.f};
      const int bb4 = lane & 3;   // batch for this B-col (cols 4-15 duplicate)
      const unsigned short* bhp = hbh + bb4 * BSTR + half * 256 + (kq << 3);
      const unsigned short* blp = hbl + bb4 * BSTR + half * 256 + (kq << 3);
      #pragma unroll
      for (int cc = 0; cc < 8; ++cc) {
        short8 bh = *(const short8*)(bhp + cc * 32);
        short8 bl = *(const short8*)(blp + cc * 32);
        aHH = __builtin_amdgcn_mfma_f32_16x16x32_bf16(wh[cc], bh, aHH, 0, 0, 0);
        aHL = __builtin_amdgcn_mfma_f32_16x16x32_bf16(wh[cc], bl, aHL, 0, 0, 0);
        aLH = __builtin_amdgcn_mfma_f32_16x16x32_bf16(wl[cc], bh, aLH, 0, 0, 0);
      }
      f32x4 acc = (aHH + aHL) + aLH;
      // D layout: col = lane&15, row = (lane>>4)*4 + reg. Keep cols 0-3.
      if (rloc < 4) {
        #pragma unroll
        for (int r = 0; r < 4; ++r)
          ghp[half][(mtile * 16 + (kq << 2) + r) * 5 + rloc] = acc[r];
      }
    }
    __syncthreads();

    // ---- gates + h_new; fast-math gates (serial critical path) ----
    if (tid < 128) {
      int bb = tid >> 5, j = tid & 31;
      float ghr = ghp[0][ j       * 5 + bb] + ghp[1][ j       * 5 + bb] + bsh[j];
      float ghz = ghp[0][(32 + j) * 5 + bb] + ghp[1][(32 + j) * 5 + bb] + bsh[32 + j];
      float ghn = ghp[0][(64 + j) * 5 + bb] + ghp[1][(64 + j) * 5 + bb] + bsh[64 + j];
      float rg = fast_sig(gxr + ghr);
      float zg = fast_sig(gxz + ghz);
      float ng = fast_tanh(gxn + rg * ghn);
      float hp = hsh[bb * HSTR + j0 + j];
      float hnew = (1.f - zg) * ng + zg * hp;
      __hip_atomic_store(
          (unsigned*)(hist + ((size_t)(bbase + bb) * T_ + t) * H_) + j0 + j,
          __float_as_uint(hnew), __ATOMIC_RELAXED, __HIP_MEMORY_SCOPE_AGENT);
    }
    __syncthreads();   // protect hsh/ghp reuse next step (R10: do not remove)
  }
}

// ---------------- sentinel fill: hist rows [t0, t0+tc) for all batches ----
__global__ __launch_bounds__(256) void sent_fill(float* hist, int t0, int tc) {
  int i = blockIdx.x * 256 + threadIdx.x;          // uint4 index
  int per = tc * (H_ >> 2);                        // uint4 per batch
  if (i < B_ * per) {
    int b = i / per, r = i % per;
    uint4* p = (uint4*)(hist + ((size_t)b * T_ + t0) * H_) + r;
    *p = make_uint4(SENT, SENT, SENT, SENT);
  }
}

__global__ __launch_bounds__(256) void conv_split(
    const float* __restrict__ A, int lda, int t0, int tc, int ltc,
    unsigned short* __restrict__ Ah, unsigned short* __restrict__ Al)
{
  int idx = blockIdx.x * 256 + threadIdx.x;
  int m = idx / (lda >> 2), kq = idx % (lda >> 2);
  const float4 v = *(const float4*)
      (A + ((size_t)(m >> ltc) * T_ + t0 + (m & (tc - 1))) * lda + (kq << 2));
  unsigned short h0 = f2bf_rne(v.x), h1 = f2bf_rne(v.y),
                 h2 = f2bf_rne(v.z), h3 = f2bf_rne(v.w);
  unsigned short l0 = f2bf_rne(v.x - bf2f(h0)), l1 = f2bf_rne(v.y - bf2f(h1)),
                 l2 = f2bf_rne(v.z - bf2f(h2)), l3 = f2bf_rne(v.w - bf2f(h3));
  size_t o = (size_t)m * lda + (kq << 2);
  *(ushort4*)(Ah + o) = make_ushort4(h0, h1, h2, h3);
  *(ushort4*)(Al + o) = make_ushort4(l0, l1, l2, l3);
}

// ---------------- split-bf16 MFMA GEMM (double-buffered, pipelined) -------
__global__ __launch_bounds__(256, 2) void gemm_mfma(
    const unsigned short* __restrict__ Ah, const unsigned short* __restrict__ Al,
    const unsigned short* __restrict__ Bh, const unsigned short* __restrict__ Bl,
    const float* __restrict__ bias, float* __restrict__ gxout, int K)
{
  __shared__ unsigned short sAh[2][128 * BKg], sAl[2][128 * BKg];
  __shared__ unsigned short sBh[2][128 * BKg], sBl[2][128 * BKg];

  const int tid = threadIdx.x;
  const int m0 = blockIdx.x << 7, n0 = blockIdx.y << 7;
  const int wave = tid >> 6, lane = tid & 63;
  const int wr = (wave & 1) << 6, wc = (wave >> 1) << 6;
  const int fm = lane & 15, kh = lane >> 4;

  const int srow = tid >> 2, sq = tid & 3;
  const int lofs0 = srow * BKg + (sq << 3);
  const int lofs1 = (64 + srow) * BKg + (sq << 3);

  f32x4 acc[4][4];
  #pragma unroll
  for (int i = 0; i < 4; ++i)
    #pragma unroll
    for (int j = 0; j < 4; ++j)
      acc[i][j] = (f32x4){0.f, 0.f, 0.f, 0.f};

  float4 pAh[2], pAl[2], pBh[2], pBl[2];
  #define PREFETCH(k0)                                                        \
    {                                                                         \
      size_t a0 = (size_t)(m0 + srow) * K + (k0) + (sq << 3);                 \
      size_t a1 = (size_t)(m0 + 64 + srow) * K + (k0) + (sq << 3);            \
      size_t b0 = (size_t)(n0 + srow) * K + (k0) + (sq << 3);                 \
      size_t b1 = (size_t)(n0 + 64 + srow) * K + (k0) + (sq << 3);            \
      pAh[0] = *(const float4*)&Ah[a0]; pAh[1] = *(const float4*)&Ah[a1];     \
      pAl[0] = *(const float4*)&Al[a0]; pAl[1] = *(const float4*)&Al[a1];     \
      pBh[0] = *(const float4*)&Bh[b0]; pBh[1] = *(const float4*)&Bh[b1];     \
      pBl[0] = *(const float4*)&Bl[b0]; pBl[1] = *(const float4*)&Bl[b1];     \
    }
  #define STORE_LDS(buf)                                                      \
    {                                                                         \
      *(float4*)&sAh[buf][lofs0] = pAh[0]; *(float4*)&sAh[buf][lofs1] = pAh[1];\
      *(float4*)&sAl[buf][lofs0] = pAl[0]; *(float4*)&sAl[buf][lofs1] = pAl[1];\
      *(float4*)&sBh[buf][lofs0] = pBh[0]; *(float4*)&sBh[buf][lofs1] = pBh[1];\
      *(float4*)&sBl[buf][lofs0] = pBl[0]; *(float4*)&sBl[buf][lofs1] = pBl[1];\
    }

  PREFETCH(0);
  STORE_LDS(0);
  int buf = 0;

  for (int k0 = 0; k0 < K; k0 += BKg) {
    __syncthreads();
    const bool more = (k0 + BKg) < K;
    if (more) PREFETCH(k0 + BKg);

    short8 fAh[4], fAl[4], fBh[4], fBl[4];
    #pragma unroll
    for (int i = 0; i < 4; ++i) {
      int ao = (wr + i * 16 + fm) * BKg + (kh << 3);
      int bo = (wc + i * 16 + fm) * BKg + (kh << 3);
      fAh[i] = *(const short8*)&sAh[buf][ao];
      fAl[i] = *(const short8*)&sAl[buf][ao];
      fBh[i] = *(const short8*)&sBh[buf][bo];
      fBl[i] = *(const short8*)&sBl[buf][bo];
    }
    #pragma unroll
    for (int i = 0; i < 4; ++i)
      #pragma unroll
      for (int j = 0; j < 4; ++j) {
        acc[i][j] = __builtin_amdgcn_mfma_f32_16x16x32_bf16(
            fAh[i], fBh[j], acc[i][j], 0, 0, 0);
        acc[i][j] = __builtin_amdgcn_mfma_f32_16x16x32_bf16(
            fAh[i], fBl[j], acc[i][j], 0, 0, 0);
        acc[i][j] = __builtin_amdgcn_mfma_f32_16x16x32_bf16(
            fAl[i], fBh[j], acc[i][j], 0, 0, 0);
      }
    if (more) {
      STORE_LDS(buf ^ 1);
      buf ^= 1;
    }
  }

  #pragma unroll
  for (int j = 0; j < 4; ++j) {
    int col = n0 + wc + j * 16 + fm;
    float bv = bias[col];
    #pragma unroll
    for (int i = 0; i < 4; ++i) {
      int rowb = m0 + wr + i * 16 + (kh << 2);
      #pragma unroll
      for (int r = 0; r < 4; ++r)
        gxout[(size_t)(rowb + r) * G3_ + col] = acc[i][j][r] + bv;
    }
  }
}

// ---------------- final FC ----------------
__global__ void fc_kernel(const float* __restrict__ hist, const float* __restrict__ Wfc,
                          const float* __restrict__ bfc, float* __restrict__ out)
{
  int b = blockIdx.x, lane = threadIdx.x;
  const float* h = hist + ((size_t)b*T_ + (T_-1))*H_;
  float acc = 0.f;
  for (int j = lane; j < H_; j += 64) acc += h[j]*Wfc[j];
  #pragma unroll
  for (int off = 32; off; off >>= 1) acc += __shfl_down(acc, off, 64);
  if (lane == 0) out[b] = acc + bfc[0];
}

extern "C" void kernel_launch(void* const* d_in, const int* in_sizes, int n_in,
                              void* d_out, int out_size, void* d_ws, size_t ws_size,
                              hipStream_t stream)
{
  const float* X    = (const float*)d_in[0];
  const float* Wih0 = (const float*)d_in[1];
  const float* Whh0 = (const float*)d_in[2];
  const float* bih0 = (const float*)d_in[3];
  const float* bhh0 = (const float*)d_in[4];
  const float* Wih1 = (const float*)d_in[5];
  const float* Whh1 = (const float*)d_in[6];
  const float* bih1 = (const float*)d_in[7];
  const float* bhh1 = (const float*)d_in[8];
  const float* Wfc  = (const float*)d_in[9];
  const float* bfc  = (const float*)d_in[10];

  float* hist = (float*)((char*)d_ws + 4096);
  const size_t histB = (size_t)B_*T_*H_*4;

  const size_t bB = (size_t)G3_ * 512 * 2;   // Wih split (hi or lo)
  const size_t wB = (size_t)G3_ * H_ * 2;    // Whh split (hi or lo)
  int tcg = 128;
  {
    size_t fixed = 4096 + histB + 2 * bB + 2 * wB;
    if      (ws_size >= fixed + (size_t)B_*512*((size_t)G3_*4 + 512*4)) tcg = 512;
    else if (ws_size >= fixed + (size_t)B_*256*((size_t)G3_*4 + 512*4)) tcg = 256;
  }
  int ltc = 31 - __builtin_clz((unsigned)tcg);

  float* gxbuf = (float*)((char*)d_ws + 4096 + histB);
  const size_t gxB = (size_t)B_*tcg*G3_*4;
  unsigned short* Ahb = (unsigned short*)((char*)gxbuf + gxB);
  const size_t aB = (size_t)B_*tcg*512*2;
  unsigned short* Alb = (unsigned short*)((char*)Ahb + aB);
  unsigned short* Bhb = (unsigned short*)((char*)Alb + aB);
  unsigned short* Blb = (unsigned short*)((char*)Bhb + bB);
  unsigned short* Whb = (unsigned short*)((char*)Blb + bB);
  unsigned short* Wlb = (unsigned short*)((char*)Whb + wB);

  const int sentGridFull = (B_ * T_ * (H_ >> 2) + 255) / 256;
  const int sentGridChunk = (B_ * tcg * (H_ >> 2) + 255) / 256;

  // layer 0: whole hist -> sentinel before its first scan (conv/gemm read X)
  hipLaunchKernelGGL(sent_fill, dim3(sentGridFull), dim3(256), 0, stream,
                     hist, 0, T_);

  for (int lay = 0; lay < 2; ++lay) {
    const float* A   = lay ? (const float*)hist : X;
    int lda          = lay ? H_ : D0_;
    const float* Wih = lay ? Wih1 : Wih0;
    const float* bih = lay ? bih1 : bih0;
    const float* Whh = lay ? Whh1 : Whh0;
    const float* bhh = lay ? bhh1 : bhh0;

    hipLaunchKernelGGL(conv_split, dim3((G3_*lda/4)/256), dim3(256), 0, stream,
                       Wih, lda, 0, 1 << 30, 30, Bhb, Blb);
    // Whh -> bf16 hi/lo for the scan's MFMA dot (R19)
    hipLaunchKernelGGL(conv_split, dim3((G3_*H_/4)/256), dim3(256), 0, stream,
                       Whh, H_, 0, 1 << 30, 30, Whb, Wlb);

    for (int t0g = 0; t0g < T_; t0g += tcg) {
      int M = B_ * tcg;
      // conv reads this chunk's hist rows (layer 1) BEFORE they're sentineled
      hipLaunchKernelGGL(conv_split, dim3((M*lda/4)/256), dim3(256), 0, stream,
                         A, lda, t0g, tcg, ltc, Ahb, Alb);
      if (lay == 1)   // re-sentinel the rows this chunk's scan will write
        hipLaunchKernelGGL(sent_fill, dim3(sentGridChunk), dim3(256), 0, stream,
                           hist, t0g, tcg);
      dim3 ggrid(M >> 7, G3_ >> 7);
      hipLaunchKernelGGL(gemm_mfma, ggrid, dim3(256), 0, stream,
                         Ahb, Alb, Bhb, Blb, bih, gxbuf, lda);
      hipLaunchKernelGGL(scan_kernel, dim3(256), dim3(768), 0, stream,
                         Whb, Wlb, bhh, (const float*)gxbuf, hist,
                         t0g, tcg, t0g, tcg);
    }
  }

  hipLaunchKernelGGL(fc_kernel, dim3(64), dim3(64), 0, stream,
                     (const float*)hist, Wfc, bfc, (float*)d_out);
}